// Round 8
// baseline (310.022 us; speedup 1.0000x reference)
//
#include <hip/hip_runtime.h>
#include <hip/hip_bf16.h>
#include <cstddef>

#define T_SEQ 1024
#define D_MODEL 512

typedef __attribute__((ext_vector_type(8))) __bf16 bf16x8;
typedef __attribute__((ext_vector_type(4))) float f32x4;
typedef __attribute__((ext_vector_type(16))) float f32x16;
typedef __attribute__((ext_vector_type(8))) unsigned short u16x8;
typedef __attribute__((ext_vector_type(4))) unsigned int u32x4;

typedef const unsigned int __attribute__((address_space(1)))* gas1_t;
typedef unsigned int __attribute__((address_space(3)))* las3_t;

__device__ __forceinline__ void gload_lds16(const void* g, void* l) {
  __builtin_amdgcn_global_load_lds((gas1_t)g, (las3_t)l, 16, 0, 0);
}

__device__ __forceinline__ float bf2f(unsigned short u) {
  return __uint_as_float(((unsigned)u) << 16);
}
__device__ __forceinline__ unsigned short f2bf(float f) {
  __hip_bfloat16 h = __float2bfloat16(f);
  return *(unsigned short*)&h;
}

#define CVTPK(dst, a, b) \
  asm("v_cvt_pk_bf16_f32 %0, %1, %2" : "=v"(dst) : "v"(a), "v"(b))

// =====================================================================
// Cast fp32 -> bf16 (each thread 8 elems)
// =====================================================================
__global__ __launch_bounds__(256)
void cast_x_kernel(const float* __restrict__ in, __hip_bfloat16* __restrict__ out) {
  const int i = (blockIdx.x * 256 + threadIdx.x) * 8;
  const float4 a = *(const float4*)(in + i);
  const float4 b = *(const float4*)(in + i + 4);
  u16x8 o;
  o[0] = f2bf(a.x); o[1] = f2bf(a.y); o[2] = f2bf(a.z); o[3] = f2bf(a.w);
  o[4] = f2bf(b.x); o[5] = f2bf(b.y); o[6] = f2bf(b.z); o[7] = f2bf(b.w);
  *(u16x8*)(out + i) = o;
}

// =====================================================================
// ALL weight prep in ONE dispatch (see slot map in launch).
// =====================================================================
__global__ __launch_bounds__(256)
void prep_weights_kernel(const float* __restrict__ loc_wq, const float* __restrict__ loc_wk,
                         const float* __restrict__ loc_wv, const float* __restrict__ g_wq,
                         const float* __restrict__ g_wk, const float* __restrict__ g_wv,
                         const float* __restrict__ out_w, const float* __restrict__ loc_wo,
                         const float* __restrict__ g_wo, __hip_bfloat16* __restrict__ WT) {
  __shared__ float tile[32][33];
  const size_t MS = (size_t)512 * 512;
  const int z = blockIdx.y;
  const float* src;
  bool tr = true;
  if (z < 3)       src = loc_wq + (size_t)z * MS;
  else if (z < 6)  src = loc_wk + (size_t)(z - 3) * MS;
  else if (z < 9)  src = loc_wv + (size_t)(z - 6) * MS;
  else if (z == 9)  src = g_wq;
  else if (z == 10) src = g_wk;
  else if (z == 11) src = g_wv;
  else if (z < 16) src = out_w + (size_t)(z - 12) * MS;
  else if (z < 19) { src = loc_wo + (size_t)(z - 16) * MS; tr = false; }
  else             { src = g_wo; tr = false; }
  __hip_bfloat16* dst = WT + (size_t)z * MS;

  const int tk = (blockIdx.x & 15) * 32;
  const int tn = (blockIdx.x >> 4) * 32;
  const int t = threadIdx.x;
  const int r = t >> 3, c4 = (t & 7) * 4;
  const float4 v = *(const float4*)(src + (size_t)(tk + r) * 512 + tn + c4);
  if (tr) {
    tile[r][c4 + 0] = v.x; tile[r][c4 + 1] = v.y;
    tile[r][c4 + 2] = v.z; tile[r][c4 + 3] = v.w;
    __syncthreads();
    ushort4 o;
    o.x = f2bf(tile[c4 + 0][r]); o.y = f2bf(tile[c4 + 1][r]);
    o.z = f2bf(tile[c4 + 2][r]); o.w = f2bf(tile[c4 + 3][r]);
    *(ushort4*)(dst + (size_t)(tn + r) * 512 + tk + c4) = o;
  } else {
    ushort4 o;
    o.x = f2bf(v.x); o.y = f2bf(v.y); o.z = f2bf(v.z); o.w = f2bf(v.w);
    *(ushort4*)(dst + (size_t)(tk + r) * 512 + tn + c4) = o;
  }
}

// cast local q/k/v biases to bf16: dst[(lv*3+role)*512 + e]
__global__ __launch_bounds__(256)
void cast_biases_kernel(const float* __restrict__ loc_bq, const float* __restrict__ loc_bk,
                        const float* __restrict__ loc_bv, __hip_bfloat16* __restrict__ dst) {
  const int i = blockIdx.x * 256 + threadIdx.x;
  if (i < 9 * 512) {
    const int which = i >> 9, lv = which / 3, role = which % 3, e = i & 511;
    const float* src = role == 0 ? loc_bq : role == 1 ? loc_bk : loc_bv;
    dst[i] = __float2bfloat16(src[lv * 512 + e]);
  }
}

// =====================================================================
// Fused bias: bfused[z][n] = bo_z @ out_w[z*512..] (+ out_b for z==0).
// =====================================================================
__global__ __launch_bounds__(256)
void bias_fuse_kernel(const float* __restrict__ loc_bo, const float* __restrict__ g_bo,
                      const float* __restrict__ out_w, const float* __restrict__ out_b,
                      float* __restrict__ bfused) {
  const int z = blockIdx.y;
  const int n = blockIdx.x * 256 + threadIdx.x;
  const float* bo = (z < 3) ? loc_bo + z * 512 : g_bo;
  const float* W = out_w + (size_t)z * 512 * 512;
  float acc = (z == 0) ? out_b[n] : 0.f;
  for (int m = 0; m < 512; ++m)
    acc = fmaf(bo[m], W[(size_t)m * 512 + n], acc);
  bfused[z * 512 + n] = acc;
}

// =====================================================================
// MFMA GEMM core v2 (m97 geometry): BM=128 BN=128 BK=32, 4 waves 2x2,
// wave tile 64x64 = acc[4][4]. ACCUMULATES into acc (caller zeros).
// =====================================================================
__device__ __forceinline__ void gemm_core_512(
    const __hip_bfloat16* __restrict__ A, const __hip_bfloat16* __restrict__ BT,
    __hip_bfloat16* As, __hip_bfloat16* Bs, int row0, int col0, f32x4 acc[4][4]) {
  const int tid = threadIdx.x;
  const int wv = tid >> 6, lane = tid & 63;
  const int g = lane >> 4, r16 = lane & 15;
  const int wm = wv >> 1, wn = wv & 1;
  const char* Ab = (const char*)A;
  const char* Bb = (const char*)BT;
  for (int k0 = 0; k0 < 512; k0 += 32) {
    // A tile 128x32 bf16 = 8KB (2 rounds)
    {
      const int row = tid >> 2, off = (tid & 3) << 4;
      gload_lds16(Ab + (size_t)(row0 + row) * 1024 + k0 * 2 + off,
                  (char*)As + (wv << 10));
      const int i2 = tid + 256;
      const int row2 = i2 >> 2, off2 = (i2 & 3) << 4;
      gload_lds16(Ab + (size_t)(row0 + row2) * 1024 + k0 * 2 + off2,
                  (char*)As + 4096 + (wv << 10));
    }
    // B tile 128x32 bf16 = 8KB (2 rounds)
    {
      const int row = tid >> 2, off = (tid & 3) << 4;
      gload_lds16(Bb + (size_t)(col0 + row) * 1024 + k0 * 2 + off,
                  (char*)Bs + (wv << 10));
      const int i2 = tid + 256;
      const int row2 = i2 >> 2, off2 = (i2 & 3) << 4;
      gload_lds16(Bb + (size_t)(col0 + row2) * 1024 + k0 * 2 + off2,
                  (char*)Bs + 4096 + (wv << 10));
    }
    __syncthreads();
    bf16x8 a[4], b[4];
#pragma unroll
    for (int m = 0; m < 4; ++m)
      a[m] = *(const bf16x8*)(As + (wm * 64 + m * 16 + r16) * 32 + g * 8);
#pragma unroll
    for (int n = 0; n < 4; ++n)
      b[n] = *(const bf16x8*)(Bs + (wn * 64 + n * 16 + r16) * 32 + g * 8);
#pragma unroll
    for (int m = 0; m < 4; ++m)
#pragma unroll
      for (int n = 0; n < 4; ++n)
        acc[m][n] = __builtin_amdgcn_mfma_f32_16x16x32_bf16(a[m], b[n], acc[m][n], 0, 0, 0);
    __syncthreads();
  }
}

// Fused Q/K/V projection: blockIdx.z selects weight slot / bias / output.
__global__ __launch_bounds__(256)
void gemm_qkv_kernel(const __hip_bfloat16* __restrict__ A,
                     const __hip_bfloat16* __restrict__ WT_base, size_t wt_stride,
                     const float* __restrict__ b0, const float* __restrict__ b1,
                     const float* __restrict__ b2,
                     __hip_bfloat16* __restrict__ out_base) {
  __shared__ __attribute__((aligned(16))) __hip_bfloat16 As[4096];
  __shared__ __attribute__((aligned(16))) __hip_bfloat16 Bs[4096];
  const int z = blockIdx.z;
  const __hip_bfloat16* WT = WT_base + (size_t)z * wt_stride;
  const float* bias = (z == 0) ? b0 : (z == 1) ? b1 : b2;
  __hip_bfloat16* C = out_base + (size_t)z * (size_t)(8192 * 512);
  const int row0 = blockIdx.y * 128, col0 = blockIdx.x * 128;
  f32x4 acc[4][4];
#pragma unroll
  for (int m = 0; m < 4; ++m)
#pragma unroll
    for (int n = 0; n < 4; ++n) acc[m][n] = (f32x4)(0.0f);
  gemm_core_512(A, WT, As, Bs, row0, col0, acc);
  const int lane = threadIdx.x & 63, wv = threadIdx.x >> 6;
  const int g = lane >> 4, r16 = lane & 15, wm = wv >> 1, wn = wv & 1;
#pragma unroll
  for (int n = 0; n < 4; ++n) {
    const int col = col0 + wn * 64 + n * 16 + r16;
    const float bn = bias[col];
#pragma unroll
    for (int m = 0; m < 4; ++m) {
      const int rowb = row0 + wm * 64 + m * 16 + g * 4;
#pragma unroll
      for (int r = 0; r < 4; ++r)
        C[(size_t)(rowb + r) * 512 + col] = __float2bfloat16(acc[m][n][r] + bn);
    }
  }
}

// Fused-weight GEMM: WfT[z] = (wo_z @ outw_z)^T, batched over z (bf16 out).
__global__ __launch_bounds__(256)
void gemm_fusew_kernel(const __hip_bfloat16* __restrict__ A_base,
                       const __hip_bfloat16* __restrict__ BT_base,
                       __hip_bfloat16* __restrict__ C_base) {
  __shared__ __attribute__((aligned(16))) __hip_bfloat16 As[4096];
  __shared__ __attribute__((aligned(16))) __hip_bfloat16 Bs[4096];
  const size_t MS = (size_t)512 * 512;
  const int z = blockIdx.z;
  const __hip_bfloat16* A = A_base + z * MS;
  const __hip_bfloat16* BT = BT_base + z * MS;
  __hip_bfloat16* C = C_base + z * MS;
  const int row0 = blockIdx.y * 128, col0 = blockIdx.x * 128;
  f32x4 acc[4][4];
#pragma unroll
  for (int m = 0; m < 4; ++m)
#pragma unroll
    for (int n = 0; n < 4; ++n) acc[m][n] = (f32x4)(0.0f);
  gemm_core_512(A, BT, As, Bs, row0, col0, acc);
  const int lane = threadIdx.x & 63, wv = threadIdx.x >> 6;
  const int g = lane >> 4, r16 = lane & 15, wm = wv >> 1, wn = wv & 1;
#pragma unroll
  for (int n = 0; n < 4; ++n) {
    const int col = col0 + wn * 64 + n * 16 + r16;
#pragma unroll
    for (int m = 0; m < 4; ++m) {
      const int rowb = row0 + wm * 64 + m * 16 + g * 4;
#pragma unroll
      for (int r = 0; r < 4; ++r)
        C[(size_t)(rowb + r) * 512 + col] = __float2bfloat16(acc[m][n][r]);
    }
  }
}

// Final fused output GEMM: out = sum_z abar_z @ Wf_z + sum_z bfused_z.
__global__ __launch_bounds__(256)
void gemm_out_fused_kernel(const __hip_bfloat16* __restrict__ A0,
                           const __hip_bfloat16* __restrict__ A1,
                           const __hip_bfloat16* __restrict__ A2,
                           const __hip_bfloat16* __restrict__ A3,
                           const __hip_bfloat16* __restrict__ WT_base,
                           const float* __restrict__ bfused,
                           float* __restrict__ out) {
  __shared__ __attribute__((aligned(16))) __hip_bfloat16 As[4096];
  __shared__ __attribute__((aligned(16))) __hip_bfloat16 Bs[4096];
  const size_t MS = (size_t)512 * 512;
  const int row0 = blockIdx.y * 128, col0 = blockIdx.x * 128;
  f32x4 acc[4][4];
#pragma unroll
  for (int m = 0; m < 4; ++m)
#pragma unroll
    for (int n = 0; n < 4; ++n) acc[m][n] = (f32x4)(0.0f);
  const __hip_bfloat16* Az[4] = {A0, A1, A2, A3};
  for (int z = 0; z < 4; ++z)
    gemm_core_512(Az[z], WT_base + (size_t)z * MS, As, Bs, row0, col0, acc);
  const int lane = threadIdx.x & 63, wv = threadIdx.x >> 6;
  const int g = lane >> 4, r16 = lane & 15, wm = wv >> 1, wn = wv & 1;
#pragma unroll
  for (int n = 0; n < 4; ++n) {
    const int col = col0 + wn * 64 + n * 16 + r16;
    const float bn = bfused[col] + bfused[512 + col] + bfused[1024 + col] +
                     bfused[1536 + col];
#pragma unroll
    for (int m = 0; m < 4; ++m) {
      const int rowb = row0 + wm * 64 + m * 16 + g * 4;
#pragma unroll
      for (int r = 0; r < 4; ++r)
        out[(size_t)(rowb + r) * 512 + col] = acc[m][n][r] + bn;
    }
  }
}

// =====================================================================
// Local windowed attention v6 — MFMA, one wave per (b,t). (proven, R7)
// =====================================================================
template <int W>
__device__ __forceinline__ const __hip_bfloat16* slot_row(
    const __hip_bfloat16* __restrict__ X, const __hip_bfloat16* __restrict__ biasb,
    int b, int tloc, int pg, int sl, int* ch_out) {
  constexpr int PAD = (W - 1) / 2;
  const int hloc = sl >> 3, p = sl & 7;
  const int m = (pg * 4 + hloc) * W + p;
  const int j = m >> 3;
  *ch_out = m & 7;
  int sr = tloc + j - PAD;
  if (p < W) {
    if (sr >= 0 && sr < T_SEQ) return X + ((size_t)(b * T_SEQ + sr) << 9);
    return biasb;
  }
  sr = sr < 0 ? 0 : (sr > T_SEQ - 1 ? T_SEQ - 1 : sr);
  return X + ((size_t)(b * T_SEQ + sr) << 9);
}

template <int W>
__global__ __launch_bounds__(256)
void local_attn_mfma_kernel(const __hip_bfloat16* __restrict__ Xq,
                            const __hip_bfloat16* __restrict__ Xk,
                            const __hip_bfloat16* __restrict__ Xv,
                            const __hip_bfloat16* __restrict__ bqb,
                            const __hip_bfloat16* __restrict__ bkb,
                            const __hip_bfloat16* __restrict__ bvb,
                            __hip_bfloat16* __restrict__ abar) {
  __shared__ unsigned lds_u[4][2048];
  const int tid = threadIdx.x;
  const int wv = tid >> 6, lane = tid & 63;
  const int bt = blockIdx.x * 4 + wv;
  const int b = bt >> 10, tloc = bt & 1023;
  unsigned* L = &lds_u[wv][0];
  const int dl = lane & 31, hi = lane >> 5;

  {
    const int k2 = dl, dhalf = hi;
    int ch0, ch1;
    const __hip_bfloat16* r0 =
        slot_row<W>(Xv, bvb, b, tloc, (2 * k2) >> 5, (2 * k2) & 31, &ch0);
    const __hip_bfloat16* r1 =
        slot_row<W>(Xv, bvb, b, tloc, (2 * k2 + 1) >> 5, (2 * k2 + 1) & 31, &ch1);
    u16x8 A0[4], A1[4];
#pragma unroll
    for (int q = 0; q < 4; ++q) {
      A0[q] = *(const u16x8*)(r0 + ch0 * 64 + dhalf * 32 + q * 8);
      A1[q] = *(const u16x8*)(r1 + ch1 * 64 + dhalf * 32 + q * 8);
    }
#pragma unroll
    for (int q = 0; q < 4; ++q)
#pragma unroll
      for (int e = 0; e < 8; ++e) {
        const int d_ = dhalf * 32 + q * 8 + e;
        const unsigned dw = (unsigned)A0[q][e] | ((unsigned)A1[q][e] << 16);
        const int byte = (d_ * 128 + k2 * 4) ^ ((d_ & 7) << 4);
        L[byte >> 2] = dw;
      }
  }

  f32x16 accP[2][2];
#pragma unroll
  for (int pg = 0; pg < 2; ++pg)
#pragma unroll
    for (int dh = 0; dh < 2; ++dh) accP[pg][dh] = (f32x16)(0.0f);

  const int myb = dl >> 3;

#pragma unroll
  for (int pg = 0; pg < 2; ++pg) {
    int chK, chQ;
    const __hip_bfloat16* rK = slot_row<W>(Xk, bkb, b, tloc, pg, dl, &chK);
    const __hip_bfloat16* rQ = slot_row<W>(Xq, bqb, b, tloc, pg, dl, &chQ);
    f32x16 sa = (f32x16)(0.0f);
#pragma unroll
    for (int i = 0; i < 4; ++i) {
      const bf16x8 kf = *(const bf16x8*)(rK + chK * 64 + i * 16 + hi * 8);
      const bf16x8 qf = *(const bf16x8*)(rQ + chQ * 64 + i * 16 + hi * 8);
      sa = __builtin_amdgcn_mfma_f32_32x32x16_bf16(kf, qf, sa, 0, 0, 0);
    }

    float sel[4];
#pragma unroll
    for (int r4 = 0; r4 < 4; ++r4)
      sel[r4] = (myb == 0) ? sa[r4]
              : (myb == 1) ? sa[4 + r4]
              : (myb == 2) ? sa[8 + r4] : sa[12 + r4];

    float mx = -3e38f;
#pragma unroll
    for (int r4 = 0; r4 < 4; ++r4)
      if (r4 + 4 * hi < W) mx = fmaxf(mx, sel[r4]);
    mx = fmaxf(mx, __shfl_xor(mx, 32));
    float e[4], ls = 0.f;
#pragma unroll
    for (int r4 = 0; r4 < 4; ++r4) {
      e[r4] = (r4 + 4 * hi < W) ? __expf(0.125f * (sel[r4] - mx)) : 0.f;
      ls += e[r4];
    }
    ls += __shfl_xor(ls, 32);
    const float inv = 1.f / ls;

    unsigned dw0, dw1;
    CVTPK(dw0, e[0] * inv, e[1] * inv);
    CVTPK(dw1, e[2] * inv, e[3] * inv);
    const unsigned q0 = __shfl_xor(dw0, 32);
    const unsigned q1 = __shfl_xor(dw1, 32);

#pragma unroll
    for (int kh = 0; kh < 2; ++kh) {
      const bool on = (2 * kh + hi) == myb;
      u32x4 bw;
      if (hi == 0) { bw[0] = dw0; bw[1] = dw1; bw[2] = q0; bw[3] = q1; }
      else         { bw[0] = q0;  bw[1] = q1;  bw[2] = dw0; bw[3] = dw1; }
      if (!on) { bw[0] = 0u; bw[1] = 0u; bw[2] = 0u; bw[3] = 0u; }
      const bf16x8 pf = __builtin_bit_cast(bf16x8, bw);
#pragma unroll
      for (int dh = 0; dh < 2; ++dh) {
        const int d_ = dh * 32 + dl;
        const int off = (d_ * 128 + pg * 64 + kh * 32 + hi * 16) ^ ((d_ & 7) << 4);
        const bf16x8 va =
            __builtin_bit_cast(bf16x8, *(const u32x4*)((const char*)L + off));
        accP[pg][dh] = __builtin_amdgcn_mfma_f32_32x32x16_bf16(va, pf, accP[pg][dh], 0, 0, 0);
      }
    }
  }

#pragma unroll
  for (int pg = 0; pg < 2; ++pg) {
    if ((dl & 7) < W) {
      const int m_o = (pg * 4 + (dl >> 3)) * W + (dl & 7);
#pragma unroll
      for (int dh = 0; dh < 2; ++dh) {
#pragma unroll
        for (int rq = 0; rq < 4; ++rq) {
          unsigned wa, wb;
          CVTPK(wa, accP[pg][dh][4 * rq + 0], accP[pg][dh][4 * rq + 1]);
          CVTPK(wb, accP[pg][dh][4 * rq + 2], accP[pg][dh][4 * rq + 3]);
          const int dwi = m_o * 34 + dh * 16 + rq * 4 + hi * 2;
          uint2 w; w.x = wa; w.y = wb;
          *(uint2*)(L + dwi) = w;
        }
      }
    }
  }
  asm volatile("s_waitcnt lgkmcnt(0)" ::: "memory");

  const int cho = lane >> 3, fb = lane & 7;
  float o[8] = {0.f, 0.f, 0.f, 0.f, 0.f, 0.f, 0.f, 0.f};
#pragma unroll
  for (int jj = 0; jj < W; ++jj) {
    const int mo = 8 * jj + cho;
    const uint2 w0 = *(const uint2*)(L + mo * 34 + fb * 4);
    const uint2 w1 = *(const uint2*)(L + mo * 34 + fb * 4 + 2);
    o[0] += bf2f((unsigned short)(w0.x & 0xffff));
    o[1] += bf2f((unsigned short)(w0.x >> 16));
    o[2] += bf2f((unsigned short)(w0.y & 0xffff));
    o[3] += bf2f((unsigned short)(w0.y >> 16));
    o[4] += bf2f((unsigned short)(w1.x & 0xffff));
    o[5] += bf2f((unsigned short)(w1.x >> 16));
    o[6] += bf2f((unsigned short)(w1.y & 0xffff));
    o[7] += bf2f((unsigned short)(w1.y >> 16));
  }
  const float invw = 1.f / (float)W;
  u16x8 ov;
#pragma unroll
  for (int e2 = 0; e2 < 8; ++e2) ov[e2] = f2bf(o[e2] * invw);
  *(u16x8*)(abar + ((size_t)bt << 9) + cho * 64 + fb * 8) = ov;
}

// =====================================================================
// Global attention v2: in-block split-KV flash, MFMA 32x32x16.
// Block = 4 waves = (wq in {0,1} q-groups of 32 rows) x (wh in {0,1} KV
// halves of 512). grid (16,64) = 1024 blocks (2x the waves of v1).
// Both halves' V^T tiles staged cooperatively per iter (dbuf, 1 barrier).
// T13 defer-rescale. End: O/m/l combine across wh via LDS (obuf aliases
// vt after final barrier; [d][q] fp32 layout conflict-free both sides).
// =====================================================================
__global__ __launch_bounds__(256)
void global_attn_mfma_kernel(const __hip_bfloat16* __restrict__ Xq,
                             const __hip_bfloat16* __restrict__ Xk,
                             const __hip_bfloat16* __restrict__ Xv,
                             __hip_bfloat16* __restrict__ att) {
  __shared__ unsigned vt[2][2][2048];   // [buf][half][8KB]
  __shared__ float ml[2][2][2][32];     // [wq][wh][m|l][q]
  const int tid = threadIdx.x;
  const int lane = tid & 63;
  const int wv = tid >> 6;
  const int wq = wv >> 1, wh = wv & 1;
  const int qblk = blockIdx.x;          // 0..15
  const int bh = blockIdx.y;            // 0..63
  const size_t base = (size_t)bh << 16;
  const int c = lane & 31;
  const int g = lane >> 5;
  const int q0 = qblk * 64 + wq * 32;

  const __hip_bfloat16* Qp = Xq + base;
  const __hip_bfloat16* Kp = Xk + base;
  const __hip_bfloat16* Vp = Xv + base;

  bf16x8 qf[4];
#pragma unroll
  for (int s = 0; s < 4; ++s)
    qf[s] = *(const bf16x8*)(Qp + (size_t)(q0 + c) * 64 + s * 16 + g * 8);

  // V staging mapping (cooperative, both halves): k2 pair, dblk 8-d block
  const int k2 = tid & 31, dblk = tid >> 5;

  bf16x8 kf[2][4];
  u16x8 vA0, vA1, vB0, vB1;

  // prologue: V tiles {0, 8}, K frags for kt = wh*8
  vA0 = *(const u16x8*)(Vp + (size_t)(2 * k2) * 64 + dblk * 8);
  vA1 = *(const u16x8*)(Vp + (size_t)(2 * k2 + 1) * 64 + dblk * 8);
  vB0 = *(const u16x8*)(Vp + (size_t)(512 + 2 * k2) * 64 + dblk * 8);
  vB1 = *(const u16x8*)(Vp + (size_t)(512 + 2 * k2 + 1) * 64 + dblk * 8);
#pragma unroll
  for (int kb = 0; kb < 2; ++kb)
#pragma unroll
    for (int s = 0; s < 4; ++s)
      kf[kb][s] = *(const bf16x8*)(Kp + (size_t)(wh * 512 + kb * 32 + c) * 64 +
                                   s * 16 + g * 8);

  f32x16 Oa = (f32x16)(0.0f), Ob = (f32x16)(0.0f);
  float m_run = -3e38f, l_run = 0.f;

  for (int i = 0; i < 8; ++i) {
    // ---- stage both halves' V^T tiles into vt[i&1] ----
    unsigned* vb0 = &vt[i & 1][0][0];
    unsigned* vb1 = &vt[i & 1][1][0];
#pragma unroll
    for (int jj = 0; jj < 8; ++jj) {
      const int d = dblk * 8 + jj;
      const int byte = (d * 128 + k2 * 4) ^ ((d & 7) << 4);
      vb0[byte >> 2] = (unsigned)vA0[jj] | ((unsigned)vA1[jj] << 16);
      vb1[byte >> 2] = (unsigned)vB0[jj] | ((unsigned)vB1[jj] << 16);
    }
    if (i < 7) {
      const __hip_bfloat16* sA = Vp + (size_t)((i + 1) * 64 + 2 * k2) * 64 + dblk * 8;
      const __hip_bfloat16* sB = sA + (size_t)512 * 64;
      vA0 = *(const u16x8*)sA;
      vA1 = *(const u16x8*)(sA + 64);
      vB0 = *(const u16x8*)sB;
      vB1 = *(const u16x8*)(sB + 64);
    }
    __syncthreads();

    // ---- QK^T for this wave's tile kt = wh*8 + i ----
    f32x16 sa = (f32x16)(0.0f), sb = (f32x16)(0.0f);
#pragma unroll
    for (int s = 0; s < 4; ++s)
      sa = __builtin_amdgcn_mfma_f32_32x32x16_bf16(kf[0][s], qf[s], sa, 0, 0, 0);
#pragma unroll
    for (int s = 0; s < 4; ++s)
      sb = __builtin_amdgcn_mfma_f32_32x32x16_bf16(kf[1][s], qf[s], sb, 0, 0, 0);

    if (i < 7) {
#pragma unroll
      for (int kb = 0; kb < 2; ++kb)
#pragma unroll
        for (int s = 0; s < 4; ++s)
          kf[kb][s] = *(const bf16x8*)(Kp + (size_t)(wh * 512 + (i + 1) * 64 + kb * 32 + c) * 64 +
                                       s * 16 + g * 8);
    }

    // ---- online softmax with defer-rescale (T13) ----
    float mx = sa[0];
#pragma unroll
    for (int r = 1; r < 16; ++r) mx = fmaxf(mx, sa[r]);
#pragma unroll
    for (int r = 0; r < 16; ++r) mx = fmaxf(mx, sb[r]);
    mx = fmaxf(mx, __shfl_xor(mx, 32));
    const float mt = mx * 0.125f;
    if (__any(mt > m_run)) {
      const float m_new = fmaxf(m_run, mt);
      const float alpha = __expf(m_run - m_new);
      m_run = m_new;
      l_run *= alpha;
#pragma unroll
      for (int r = 0; r < 16; ++r) { Oa[r] *= alpha; Ob[r] *= alpha; }
    }

    float p0[16], p1[16];
    float lsum = 0.f;
#pragma unroll
    for (int r = 0; r < 16; ++r) { p0[r] = __expf(fmaf(sa[r], 0.125f, -m_run)); lsum += p0[r]; }
#pragma unroll
    for (int r = 0; r < 16; ++r) { p1[r] = __expf(fmaf(sb[r], 0.125f, -m_run)); lsum += p1[r]; }
    lsum += __shfl_xor(lsum, 32);
    l_run += lsum;

    // ---- redistribute P ----
    unsigned bw[2][2][4];
#define REDIST(pb, kb_)                                                  \
    {                                                                    \
      unsigned t0_, t1_, t2_, t3_, t4_, t5_, t6_, t7_;                   \
      CVTPK(t0_, pb[0], pb[1]);   CVTPK(t1_, pb[2], pb[3]);              \
      CVTPK(t2_, pb[4], pb[5]);   CVTPK(t3_, pb[6], pb[7]);              \
      CVTPK(t4_, pb[8], pb[9]);   CVTPK(t5_, pb[10], pb[11]);            \
      CVTPK(t6_, pb[12], pb[13]); CVTPK(t7_, pb[14], pb[15]);            \
      { const unsigned ax = __shfl_xor(t0_, 32), bx = __shfl_xor(t2_, 32); \
        const bool lo_ = lane < 32;                                      \
        const unsigned na = lo_ ? t0_ : bx, nb = lo_ ? ax : t2_;         \
        t0_ = na; t2_ = nb; }                                            \
      { const unsigned ax = __shfl_xor(t1_, 32), bx = __shfl_xor(t3_, 32); \
        const bool lo_ = lane < 32;                                      \
        const unsigned na = lo_ ? t1_ : bx, nb = lo_ ? ax : t3_;         \
        t1_ = na; t3_ = nb; }                                            \
      { const unsigned ax = __shfl_xor(t4_, 32), bx = __shfl_xor(t6_, 32); \
        const bool lo_ = lane < 32;                                      \
        const unsigned na = lo_ ? t4_ : bx, nb = lo_ ? ax : t6_;         \
        t4_ = na; t6_ = nb; }                                            \
      { const unsigned ax = __shfl_xor(t5_, 32), bx = __shfl_xor(t7_, 32); \
        const bool lo_ = lane < 32;                                      \
        const unsigned na = lo_ ? t5_ : bx, nb = lo_ ? ax : t7_;         \
        t5_ = na; t7_ = nb; }                                            \
      bw[kb_][0][0] = t0_; bw[kb_][0][1] = t1_; bw[kb_][0][2] = t2_;     \
      bw[kb_][0][3] = t3_;                                               \
      bw[kb_][1][0] = t4_; bw[kb_][1][1] = t5_; bw[kb_][1][2] = t6_;     \
      bw[kb_][1][3] = t7_;                                               \
    }
    REDIST(p0, 0)
    REDIST(p1, 1)
#undef REDIST

    // ---- PV from this wave's half tile ----
    const unsigned* vbr = &vt[i & 1][wh][0];
#pragma unroll
    for (int kb = 0; kb < 2; ++kb)
#pragma unroll
      for (int st = 0; st < 2; ++st) {
        const u32x4 pw = { bw[kb][st][0], bw[kb][st][1], bw[kb][st][2], bw[kb][st][3] };
        const bf16x8 pf = __builtin_bit_cast(bf16x8, pw);
        {
          const int row = c;
          const int off = (row * 128 + (kb * 64 + st * 32 + g * 16)) ^ ((row & 7) << 4);
          const bf16x8 va = __builtin_bit_cast(bf16x8, *(const u32x4*)((const char*)vbr + off));
          Oa = __builtin_amdgcn_mfma_f32_32x32x16_bf16(va, pf, Oa, 0, 0, 0);
        }
        {
          const int row = 32 + c;
          const int off = (row * 128 + (kb * 64 + st * 32 + g * 16)) ^ ((row & 7) << 4);
          const bf16x8 va = __builtin_bit_cast(bf16x8, *(const u32x4*)((const char*)vbr + off));
          Ob = __builtin_amdgcn_mfma_f32_32x32x16_bf16(va, pf, Ob, 0, 0, 0);
        }
      }
  }

  // ---- combine the two KV halves ----
  __syncthreads();                       // all PV reads done; vt reusable
  float* obuf = (float*)&vt[0][0][0];    // [wq][64 d][32 q] fp32 (16 KB)
  if (lane < 32) {
    ml[wq][wh][0][lane] = m_run;
    ml[wq][wh][1][lane] = l_run;
  }
  __syncthreads();
  const float mo = ml[wq][1 - wh][0][c];
  const float lo = ml[wq][1 - wh][1][c];
  const float M = fmaxf(m_run, mo);
  const float sc = __expf(m_run - M);
  if (wh == 1) {
    float* ob = obuf + wq * 2048;
#pragma unroll
    for (int r = 0; r < 16; ++r) {
      const int d = (r & 3) + 8 * (r >> 2) + 4 * g;
      ob[d * 32 + c] = Oa[r] * sc;
      ob[(32 + d) * 32 + c] = Ob[r] * sc;
    }
  }
  __syncthreads();
  if (wh == 0) {
    const float lfin = l_run * sc + lo * __expf(mo - M);
    const float inv = 1.f / lfin;
    const float* ob = obuf + wq * 2048;
    __hip_bfloat16* drow = att + base + (size_t)(q0 + c) * 64;
#pragma unroll
    for (int qd = 0; qd < 4; ++qd) {
      const int d0 = 8 * qd + 4 * g;
      unsigned lo_, hi_;
      {
        const float a0 = (Oa[4 * qd + 0] * sc + ob[(d0 + 0) * 32 + c]) * inv;
        const float a1 = (Oa[4 * qd + 1] * sc + ob[(d0 + 1) * 32 + c]) * inv;
        const float a2 = (Oa[4 * qd + 2] * sc + ob[(d0 + 2) * 32 + c]) * inv;
        const float a3 = (Oa[4 * qd + 3] * sc + ob[(d0 + 3) * 32 + c]) * inv;
        CVTPK(lo_, a0, a1); CVTPK(hi_, a2, a3);
        uint2 w; w.x = lo_; w.y = hi_;
        *(uint2*)(drow + d0) = w;
      }
      {
        const float a0 = (Ob[4 * qd + 0] * sc + ob[(32 + d0 + 0) * 32 + c]) * inv;
        const float a1 = (Ob[4 * qd + 1] * sc + ob[(32 + d0 + 1) * 32 + c]) * inv;
        const float a2 = (Ob[4 * qd + 2] * sc + ob[(32 + d0 + 2) * 32 + c]) * inv;
        const float a3 = (Ob[4 * qd + 3] * sc + ob[(32 + d0 + 3) * 32 + c]) * inv;
        CVTPK(lo_, a0, a1); CVTPK(hi_, a2, a3);
        uint2 w; w.x = lo_; w.y = hi_;
        *(uint2*)(drow + 32 + d0) = w;
      }
    }
  }
}

// =====================================================================
// Launch
// =====================================================================
extern "C" void kernel_launch(void* const* d_in, const int* in_sizes, int n_in,
                              void* d_out, int out_size, void* d_ws, size_t ws_size,
                              hipStream_t stream) {
  const float* x      = (const float*)d_in[0];
  const float* loc_wq = (const float*)d_in[1];
  const float* loc_bq = (const float*)d_in[2];
  const float* loc_wk = (const float*)d_in[3];
  const float* loc_bk = (const float*)d_in[4];
  const float* loc_wv = (const float*)d_in[5];
  const float* loc_bv = (const float*)d_in[6];
  const float* loc_wo = (const float*)d_in[7];
  const float* loc_bo = (const float*)d_in[8];
  const float* g_wq  = (const float*)d_in[9];
  const float* g_bq  = (const float*)d_in[10];
  const float* g_wk  = (const float*)d_in[11];
  const float* g_bk  = (const float*)d_in[12];
  const float* g_wv  = (const float*)d_in[13];
  const float* g_bv  = (const float*)d_in[14];
  const float* g_wo  = (const float*)d_in[15];
  const float* g_bo  = (const float*)d_in[16];
  const float* out_w = (const float*)d_in[17];
  const float* out_b = (const float*)d_in[18];
  float* out = (float*)d_out;

  __hip_bfloat16* wsb = (__hip_bfloat16*)d_ws;
  const size_t SZ = (size_t)8192 * 512;
  const size_t MS = (size_t)512 * 512;
  // WT slots: 0-8 loc qkv, 9-11 g qkv, 12-15 outw^T, 16-18 loc_wo (plain),
  //           19 g_wo (plain), 20-23 Wfused^T
  __hip_bfloat16* xb    = wsb;
  __hip_bfloat16* WT    = wsb + SZ;
  __hip_bfloat16* Xq    = wsb + SZ + 24 * MS;
  __hip_bfloat16* Xk    = Xq + SZ;
  __hip_bfloat16* Xv    = Xq + 2 * SZ;
  __hip_bfloat16* abar0 = Xq + 3 * SZ;
  __hip_bfloat16* abar1 = Xq + 4 * SZ;
  __hip_bfloat16* abar2 = Xq + 5 * SZ;
  __hip_bfloat16* abar3 = Xq + 6 * SZ;
  float* bfused = (float*)(Xq + 7 * SZ);                    // 4 x 512 fp32
  __hip_bfloat16* bqkvb = (__hip_bfloat16*)(bfused + 2048); // 9 x 512 bf16
  __hip_bfloat16* abars[3] = {abar0, abar1, abar2};

  const dim3 thr(256);

  // ---- one-time prep ----
  cast_x_kernel<<<2048, thr, 0, stream>>>(x, xb);
  prep_weights_kernel<<<dim3(256, 20), thr, 0, stream>>>(
      loc_wq, loc_wk, loc_wv, g_wq, g_wk, g_wv, out_w, loc_wo, g_wo, WT);
  cast_biases_kernel<<<18, thr, 0, stream>>>(loc_bq, loc_bk, loc_bv, bqkvb);
  gemm_fusew_kernel<<<dim3(4, 4, 4), thr, 0, stream>>>(WT + 12 * MS, WT + 16 * MS,
                                                       WT + 20 * MS);
  bias_fuse_kernel<<<dim3(2, 4), thr, 0, stream>>>(loc_bo, g_bo, out_w, out_b, bfused);

  const dim3 ggrid(4, 64);         // N/128, M/128
  const dim3 gqkv(4, 64, 3);

  for (int lv = 0; lv < 3; ++lv) {
    gemm_qkv_kernel<<<gqkv, thr, 0, stream>>>(
        xb, WT + lv * MS, 3 * MS,
        loc_bq + lv * 512, loc_bk + lv * 512, loc_bv + lv * 512, Xq);

    const __hip_bfloat16* bqb = bqkvb + (lv * 3 + 0) * 512;
    const __hip_bfloat16* bkb = bqkvb + (lv * 3 + 1) * 512;
    const __hip_bfloat16* bvb = bqkvb + (lv * 3 + 2) * 512;
    if (lv == 0)
      local_attn_mfma_kernel<3><<<2048, thr, 0, stream>>>(Xq, Xk, Xv, bqb, bkb, bvb, abars[lv]);
    else if (lv == 1)
      local_attn_mfma_kernel<5><<<2048, thr, 0, stream>>>(Xq, Xk, Xv, bqb, bkb, bvb, abars[lv]);
    else
      local_attn_mfma_kernel<7><<<2048, thr, 0, stream>>>(Xq, Xk, Xv, bqb, bkb, bvb, abars[lv]);
  }

  // global branch
  gemm_qkv_kernel<<<gqkv, thr, 0, stream>>>(xb, WT + 9 * MS, MS, g_bq, g_bk, g_bv, Xq);
  global_attn_mfma_kernel<<<dim3(16, 64), thr, 0, stream>>>(Xq, Xk, Xv, abar3);

  // fused output projection: one K=2048 GEMM, out written once
  gemm_out_fused_kernel<<<ggrid, thr, 0, stream>>>(abar0, abar1, abar2, abar3,
                                                   WT + 20 * MS, bfused, out);
}

// Round 9
// 290.110 us; speedup vs baseline: 1.0686x; 1.0686x over previous
//
#include <hip/hip_runtime.h>
#include <hip/hip_bf16.h>
#include <cstddef>

#define T_SEQ 1024
#define D_MODEL 512

typedef __attribute__((ext_vector_type(8))) __bf16 bf16x8;
typedef __attribute__((ext_vector_type(4))) float f32x4;
typedef __attribute__((ext_vector_type(16))) float f32x16;
typedef __attribute__((ext_vector_type(8))) unsigned short u16x8;
typedef __attribute__((ext_vector_type(4))) unsigned int u32x4;

typedef const unsigned int __attribute__((address_space(1)))* gas1_t;
typedef unsigned int __attribute__((address_space(3)))* las3_t;

__device__ __forceinline__ void gload_lds16(const void* g, void* l) {
  __builtin_amdgcn_global_load_lds((gas1_t)g, (las3_t)l, 16, 0, 0);
}

__device__ __forceinline__ float bf2f(unsigned short u) {
  return __uint_as_float(((unsigned)u) << 16);
}
__device__ __forceinline__ unsigned short f2bf(float f) {
  __hip_bfloat16 h = __float2bfloat16(f);
  return *(unsigned short*)&h;
}

#define CVTPK(dst, a, b) \
  asm("v_cvt_pk_bf16_f32 %0, %1, %2" : "=v"(dst) : "v"(a), "v"(b))

// exchange lane halves between two dwords (global attn P redistribution)
__device__ __forceinline__ void swap32(unsigned& a, unsigned& b, int lane) {
  const unsigned ax = __shfl_xor(a, 32);
  const unsigned bx = __shfl_xor(b, 32);
  const bool lo = lane < 32;
  const unsigned na = lo ? a : bx;
  const unsigned nb = lo ? ax : b;
  a = na; b = nb;
}

// =====================================================================
// ALL prep in ONE dispatch. z = blockIdx.y:
//  0-2 loc_wq (T), 3-5 loc_wk (T), 6-8 loc_wv (T), 9 g_wq (T), 10 g_wk (T),
//  11 g_wv (T), 12-15 out_w (T), 16-18 loc_wo (cast), 19 g_wo (cast),
//  20 x fp32->bf16 cast, 21 q/k/v bias casts.
// =====================================================================
__global__ __launch_bounds__(256)
void prep_weights_kernel(const float* __restrict__ loc_wq, const float* __restrict__ loc_wk,
                         const float* __restrict__ loc_wv, const float* __restrict__ g_wq,
                         const float* __restrict__ g_wk, const float* __restrict__ g_wv,
                         const float* __restrict__ out_w, const float* __restrict__ loc_wo,
                         const float* __restrict__ g_wo, const float* __restrict__ x,
                         const float* __restrict__ loc_bq, const float* __restrict__ loc_bk,
                         const float* __restrict__ loc_bv,
                         __hip_bfloat16* __restrict__ WT, __hip_bfloat16* __restrict__ xb,
                         __hip_bfloat16* __restrict__ bqkvb) {
  __shared__ float tile[32][33];
  const size_t MS = (size_t)512 * 512;
  const int z = blockIdx.y;
  const int t = threadIdx.x;

  if (z == 20) {   // cast x: 4.19M elems over 256 blocks, 64/thread
    const int base = blockIdx.x * 16384 + t * 8;
#pragma unroll
    for (int it = 0; it < 8; ++it) {
      const int i = base + it * 2048;
      const float4 a = *(const float4*)(x + i);
      const float4 b = *(const float4*)(x + i + 4);
      u16x8 o;
      o[0] = f2bf(a.x); o[1] = f2bf(a.y); o[2] = f2bf(a.z); o[3] = f2bf(a.w);
      o[4] = f2bf(b.x); o[5] = f2bf(b.y); o[6] = f2bf(b.z); o[7] = f2bf(b.w);
      *(u16x8*)(xb + i) = o;
    }
    return;
  }
  if (z == 21) {   // cast q/k/v biases: 9*512 elems in 18 blocks
    const int i = blockIdx.x * 256 + t;
    if (blockIdx.x < 18) {
      const int which = i >> 9, lv = which / 3, role = which % 3, e = i & 511;
      const float* src = role == 0 ? loc_bq : role == 1 ? loc_bk : loc_bv;
      bqkvb[i] = __float2bfloat16(src[lv * 512 + e]);
    }
    return;
  }

  const float* src;
  bool tr = true;
  if (z < 3)       src = loc_wq + (size_t)z * MS;
  else if (z < 6)  src = loc_wk + (size_t)(z - 3) * MS;
  else if (z < 9)  src = loc_wv + (size_t)(z - 6) * MS;
  else if (z == 9)  src = g_wq;
  else if (z == 10) src = g_wk;
  else if (z == 11) src = g_wv;
  else if (z < 16) src = out_w + (size_t)(z - 12) * MS;
  else if (z < 19) { src = loc_wo + (size_t)(z - 16) * MS; tr = false; }
  else             { src = g_wo; tr = false; }
  __hip_bfloat16* dst = WT + (size_t)z * MS;

  const int tk = (blockIdx.x & 15) * 32;
  const int tn = (blockIdx.x >> 4) * 32;
  const int r = t >> 3, c4 = (t & 7) * 4;
  const float4 v = *(const float4*)(src + (size_t)(tk + r) * 512 + tn + c4);
  if (tr) {
    tile[r][c4 + 0] = v.x; tile[r][c4 + 1] = v.y;
    tile[r][c4 + 2] = v.z; tile[r][c4 + 3] = v.w;
    __syncthreads();
    ushort4 o;
    o.x = f2bf(tile[c4 + 0][r]); o.y = f2bf(tile[c4 + 1][r]);
    o.z = f2bf(tile[c4 + 2][r]); o.w = f2bf(tile[c4 + 3][r]);
    *(ushort4*)(dst + (size_t)(tn + r) * 512 + tk + c4) = o;
  } else {
    ushort4 o;
    o.x = f2bf(v.x); o.y = f2bf(v.y); o.z = f2bf(v.z); o.w = f2bf(v.w);
    *(ushort4*)(dst + (size_t)(tk + r) * 512 + tn + c4) = o;
  }
}

// =====================================================================
// Fused bias: bfused[z][n] = bo_z @ out_w[z*512..] (+ out_b for z==0).
// =====================================================================
__global__ __launch_bounds__(256)
void bias_fuse_kernel(const float* __restrict__ loc_bo, const float* __restrict__ g_bo,
                      const float* __restrict__ out_w, const float* __restrict__ out_b,
                      float* __restrict__ bfused) {
  const int z = blockIdx.y;
  const int n = blockIdx.x * 256 + threadIdx.x;
  const float* bo = (z < 3) ? loc_bo + z * 512 : g_bo;
  const float* W = out_w + (size_t)z * 512 * 512;
  float acc = (z == 0) ? out_b[n] : 0.f;
  for (int m = 0; m < 512; ++m)
    acc = fmaf(bo[m], W[(size_t)m * 512 + n], acc);
  bfused[z * 512 + n] = acc;
}

// =====================================================================
// MFMA GEMM core, BM=128 BN=128 BK=32 (m97 geometry). ACCUMULATES.
// =====================================================================
__device__ __forceinline__ void gemm_core_b128(
    const __hip_bfloat16* __restrict__ A, const __hip_bfloat16* __restrict__ BT,
    __hip_bfloat16* As, __hip_bfloat16* Bs, int row0, int col0, f32x4 acc[4][4]) {
  const int tid = threadIdx.x;
  const int wv = tid >> 6, lane = tid & 63;
  const int g = lane >> 4, r16 = lane & 15;
  const int wm = wv >> 1, wn = wv & 1;
  const char* Ab = (const char*)A;
  const char* Bb = (const char*)BT;
  for (int k0 = 0; k0 < 512; k0 += 32) {
    {
      const int row = tid >> 2, off = (tid & 3) << 4;
      gload_lds16(Ab + (size_t)(row0 + row) * 1024 + k0 * 2 + off,
                  (char*)As + (wv << 10));
      const int i2 = tid + 256;
      const int row2 = i2 >> 2, off2 = (i2 & 3) << 4;
      gload_lds16(Ab + (size_t)(row0 + row2) * 1024 + k0 * 2 + off2,
                  (char*)As + 4096 + (wv << 10));
    }
    {
      const int row = tid >> 2, off = (tid & 3) << 4;
      gload_lds16(Bb + (size_t)(col0 + row) * 1024 + k0 * 2 + off,
                  (char*)Bs + (wv << 10));
      const int i2 = tid + 256;
      const int row2 = i2 >> 2, off2 = (i2 & 3) << 4;
      gload_lds16(Bb + (size_t)(col0 + row2) * 1024 + k0 * 2 + off2,
                  (char*)Bs + 4096 + (wv << 10));
    }
    __syncthreads();
    bf16x8 a[4], b[4];
#pragma unroll
    for (int m = 0; m < 4; ++m)
      a[m] = *(const bf16x8*)(As + (wm * 64 + m * 16 + r16) * 32 + g * 8);
#pragma unroll
    for (int n = 0; n < 4; ++n)
      b[n] = *(const bf16x8*)(Bs + (wn * 64 + n * 16 + r16) * 32 + g * 8);
#pragma unroll
    for (int m = 0; m < 4; ++m)
#pragma unroll
      for (int n = 0; n < 4; ++n)
        acc[m][n] = __builtin_amdgcn_mfma_f32_16x16x32_bf16(a[m], b[n], acc[m][n], 0, 0, 0);
    __syncthreads();
  }
}

// BM=64 variant (2 blocks/CU at grid 512) — for the single-unit out GEMM.
__device__ __forceinline__ void gemm_core_b64(
    const __hip_bfloat16* __restrict__ A, const __hip_bfloat16* __restrict__ BT,
    __hip_bfloat16* As, __hip_bfloat16* Bs, int row0, int col0, f32x4 acc[2][4]) {
  const int tid = threadIdx.x;
  const int wv = tid >> 6, lane = tid & 63;
  const int g = lane >> 4, r16 = lane & 15;
  const int wm = wv >> 1, wn = wv & 1;
  const char* Ab = (const char*)A;
  const char* Bb = (const char*)BT;
  for (int k0 = 0; k0 < 512; k0 += 32) {
    {
      const int row = tid >> 2, off = (tid & 3) << 4;
      gload_lds16(Ab + (size_t)(row0 + row) * 1024 + k0 * 2 + off,
                  (char*)As + (wv << 10));
    }
    {
      const int row = tid >> 2, off = (tid & 3) << 4;
      gload_lds16(Bb + (size_t)(col0 + row) * 1024 + k0 * 2 + off,
                  (char*)Bs + (wv << 10));
      const int i2 = tid + 256;
      const int row2 = i2 >> 2, off2 = (i2 & 3) << 4;
      gload_lds16(Bb + (size_t)(col0 + row2) * 1024 + k0 * 2 + off2,
                  (char*)Bs + 4096 + (wv << 10));
    }
    __syncthreads();
    bf16x8 a[2], b[4];
#pragma unroll
    for (int m = 0; m < 2; ++m)
      a[m] = *(const bf16x8*)(As + (wm * 32 + m * 16 + r16) * 32 + g * 8);
#pragma unroll
    for (int n = 0; n < 4; ++n)
      b[n] = *(const bf16x8*)(Bs + (wn * 64 + n * 16 + r16) * 32 + g * 8);
#pragma unroll
    for (int m = 0; m < 2; ++m)
#pragma unroll
      for (int n = 0; n < 4; ++n)
        acc[m][n] = __builtin_amdgcn_mfma_f32_16x16x32_bf16(a[m], b[n], acc[m][n], 0, 0, 0);
    __syncthreads();
  }
}

// Fused Q/K/V projection (BM=128): blockIdx.z selects slot/bias/output.
__global__ __launch_bounds__(256)
void gemm_qkv_kernel(const __hip_bfloat16* __restrict__ A,
                     const __hip_bfloat16* __restrict__ WT_base, size_t wt_stride,
                     const float* __restrict__ b0, const float* __restrict__ b1,
                     const float* __restrict__ b2,
                     __hip_bfloat16* __restrict__ out_base) {
  __shared__ __attribute__((aligned(16))) __hip_bfloat16 As[4096];
  __shared__ __attribute__((aligned(16))) __hip_bfloat16 Bs[4096];
  const int z = blockIdx.z;
  const __hip_bfloat16* WT = WT_base + (size_t)z * wt_stride;
  const float* bias = (z == 0) ? b0 : (z == 1) ? b1 : b2;
  __hip_bfloat16* C = out_base + (size_t)z * (size_t)(8192 * 512);
  const int row0 = blockIdx.y * 128, col0 = blockIdx.x * 128;
  f32x4 acc[4][4];
#pragma unroll
  for (int m = 0; m < 4; ++m)
#pragma unroll
    for (int n = 0; n < 4; ++n) acc[m][n] = (f32x4)(0.0f);
  gemm_core_b128(A, WT, As, Bs, row0, col0, acc);
  const int lane = threadIdx.x & 63, wv = threadIdx.x >> 6;
  const int g = lane >> 4, r16 = lane & 15, wm = wv >> 1, wn = wv & 1;
#pragma unroll
  for (int n = 0; n < 4; ++n) {
    const int col = col0 + wn * 64 + n * 16 + r16;
    const float bn = bias[col];
#pragma unroll
    for (int m = 0; m < 4; ++m) {
      const int rowb = row0 + wm * 64 + m * 16 + g * 4;
#pragma unroll
      for (int r = 0; r < 4; ++r)
        C[(size_t)(rowb + r) * 512 + col] = __float2bfloat16(acc[m][n][r] + bn);
    }
  }
}

// Fused-weight GEMM: WfT[z] = (wo_z @ outw_z)^T (BM=128, batched z).
__global__ __launch_bounds__(256)
void gemm_fusew_kernel(const __hip_bfloat16* __restrict__ A_base,
                       const __hip_bfloat16* __restrict__ BT_base,
                       __hip_bfloat16* __restrict__ C_base) {
  __shared__ __attribute__((aligned(16))) __hip_bfloat16 As[4096];
  __shared__ __attribute__((aligned(16))) __hip_bfloat16 Bs[4096];
  const size_t MS = (size_t)512 * 512;
  const int z = blockIdx.z;
  const __hip_bfloat16* A = A_base + z * MS;
  const __hip_bfloat16* BT = BT_base + z * MS;
  __hip_bfloat16* C = C_base + z * MS;
  const int row0 = blockIdx.y * 128, col0 = blockIdx.x * 128;
  f32x4 acc[4][4];
#pragma unroll
  for (int m = 0; m < 4; ++m)
#pragma unroll
    for (int n = 0; n < 4; ++n) acc[m][n] = (f32x4)(0.0f);
  gemm_core_b128(A, BT, As, Bs, row0, col0, acc);
  const int lane = threadIdx.x & 63, wv = threadIdx.x >> 6;
  const int g = lane >> 4, r16 = lane & 15, wm = wv >> 1, wn = wv & 1;
#pragma unroll
  for (int n = 0; n < 4; ++n) {
    const int col = col0 + wn * 64 + n * 16 + r16;
#pragma unroll
    for (int m = 0; m < 4; ++m) {
      const int rowb = row0 + wm * 64 + m * 16 + g * 4;
#pragma unroll
      for (int r = 0; r < 4; ++r)
        C[(size_t)(rowb + r) * 512 + col] = __float2bfloat16(acc[m][n][r]);
    }
  }
}

// Final fused output GEMM (BM=64, grid (4,128) = 2 blocks/CU):
// out = sum_z abar_z @ Wf_z + sum_z bfused_z.
__global__ __launch_bounds__(256)
void gemm_out_fused_kernel(const __hip_bfloat16* __restrict__ A0,
                           const __hip_bfloat16* __restrict__ A1,
                           const __hip_bfloat16* __restrict__ A2,
                           const __hip_bfloat16* __restrict__ A3,
                           const __hip_bfloat16* __restrict__ WT_base,
                           const float* __restrict__ bfused,
                           float* __restrict__ out) {
  __shared__ __attribute__((aligned(16))) __hip_bfloat16 As[2048];
  __shared__ __attribute__((aligned(16))) __hip_bfloat16 Bs[4096];
  const size_t MS = (size_t)512 * 512;
  const int row0 = blockIdx.y * 64, col0 = blockIdx.x * 128;
  f32x4 acc[2][4];
#pragma unroll
  for (int m = 0; m < 2; ++m)
#pragma unroll
    for (int n = 0; n < 4; ++n) acc[m][n] = (f32x4)(0.0f);
  const __hip_bfloat16* Az[4] = {A0, A1, A2, A3};
  for (int z = 0; z < 4; ++z)
    gemm_core_b64(Az[z], WT_base + (size_t)z * MS, As, Bs, row0, col0, acc);
  const int lane = threadIdx.x & 63, wv = threadIdx.x >> 6;
  const int g = lane >> 4, r16 = lane & 15, wm = wv >> 1, wn = wv & 1;
#pragma unroll
  for (int n = 0; n < 4; ++n) {
    const int col = col0 + wn * 64 + n * 16 + r16;
    const float bn = bfused[col] + bfused[512 + col] + bfused[1024 + col] +
                     bfused[1536 + col];
#pragma unroll
    for (int m = 0; m < 2; ++m) {
      const int rowb = row0 + wm * 32 + m * 16 + g * 4;
#pragma unroll
      for (int r = 0; r < 4; ++r)
        out[(size_t)(rowb + r) * 512 + col] = acc[m][n][r] + bn;
    }
  }
}

// =====================================================================
// Local windowed attention — MFMA, one wave per (b,t). (proven, R7)
// =====================================================================
template <int W>
__device__ __forceinline__ const __hip_bfloat16* slot_row(
    const __hip_bfloat16* __restrict__ X, const __hip_bfloat16* __restrict__ biasb,
    int b, int tloc, int pg, int sl, int* ch_out) {
  constexpr int PAD = (W - 1) / 2;
  const int hloc = sl >> 3, p = sl & 7;
  const int m = (pg * 4 + hloc) * W + p;
  const int j = m >> 3;
  *ch_out = m & 7;
  int sr = tloc + j - PAD;
  if (p < W) {
    if (sr >= 0 && sr < T_SEQ) return X + ((size_t)(b * T_SEQ + sr) << 9);
    return biasb;
  }
  sr = sr < 0 ? 0 : (sr > T_SEQ - 1 ? T_SEQ - 1 : sr);
  return X + ((size_t)(b * T_SEQ + sr) << 9);
}

template <int W>
__global__ __launch_bounds__(256)
void local_attn_mfma_kernel(const __hip_bfloat16* __restrict__ Xq,
                            const __hip_bfloat16* __restrict__ Xk,
                            const __hip_bfloat16* __restrict__ Xv,
                            const __hip_bfloat16* __restrict__ bqb,
                            const __hip_bfloat16* __restrict__ bkb,
                            const __hip_bfloat16* __restrict__ bvb,
                            __hip_bfloat16* __restrict__ abar) {
  __shared__ unsigned lds_u[4][2048];
  const int tid = threadIdx.x;
  const int wv = tid >> 6, lane = tid & 63;
  const int bt = blockIdx.x * 4 + wv;
  const int b = bt >> 10, tloc = bt & 1023;
  unsigned* L = &lds_u[wv][0];
  const int dl = lane & 31, hi = lane >> 5;

  {
    const int k2 = dl, dhalf = hi;
    int ch0, ch1;
    const __hip_bfloat16* r0 =
        slot_row<W>(Xv, bvb, b, tloc, (2 * k2) >> 5, (2 * k2) & 31, &ch0);
    const __hip_bfloat16* r1 =
        slot_row<W>(Xv, bvb, b, tloc, (2 * k2 + 1) >> 5, (2 * k2 + 1) & 31, &ch1);
    u16x8 A0[4], A1[4];
#pragma unroll
    for (int q = 0; q < 4; ++q) {
      A0[q] = *(const u16x8*)(r0 + ch0 * 64 + dhalf * 32 + q * 8);
      A1[q] = *(const u16x8*)(r1 + ch1 * 64 + dhalf * 32 + q * 8);
    }
#pragma unroll
    for (int q = 0; q < 4; ++q)
#pragma unroll
      for (int e = 0; e < 8; ++e) {
        const int d_ = dhalf * 32 + q * 8 + e;
        const unsigned dw = (unsigned)A0[q][e] | ((unsigned)A1[q][e] << 16);
        const int byte = (d_ * 128 + k2 * 4) ^ ((d_ & 7) << 4);
        L[byte >> 2] = dw;
      }
  }

  f32x16 accP[2][2];
#pragma unroll
  for (int pg = 0; pg < 2; ++pg)
#pragma unroll
    for (int dh = 0; dh < 2; ++dh) accP[pg][dh] = (f32x16)(0.0f);

  const int myb = dl >> 3;

#pragma unroll
  for (int pg = 0; pg < 2; ++pg) {
    int chK, chQ;
    const __hip_bfloat16* rK = slot_row<W>(Xk, bkb, b, tloc, pg, dl, &chK);
    const __hip_bfloat16* rQ = slot_row<W>(Xq, bqb, b, tloc, pg, dl, &chQ);
    f32x16 sa = (f32x16)(0.0f);
#pragma unroll
    for (int i = 0; i < 4; ++i) {
      const bf16x8 kf = *(const bf16x8*)(rK + chK * 64 + i * 16 + hi * 8);
      const bf16x8 qf = *(const bf16x8*)(rQ + chQ * 64 + i * 16 + hi * 8);
      sa = __builtin_amdgcn_mfma_f32_32x32x16_bf16(kf, qf, sa, 0, 0, 0);
    }

    float sel[4];
#pragma unroll
    for (int r4 = 0; r4 < 4; ++r4)
      sel[r4] = (myb == 0) ? sa[r4]
              : (myb == 1) ? sa[4 + r4]
              : (myb == 2) ? sa[8 + r4] : sa[12 + r4];

    float mx = -3e38f;
#pragma unroll
    for (int r4 = 0; r4 < 4; ++r4)
      if (r4 + 4 * hi < W) mx = fmaxf(mx, sel[r4]);
    mx = fmaxf(mx, __shfl_xor(mx, 32));
    float e[4], ls = 0.f;
#pragma unroll
    for (int r4 = 0; r4 < 4; ++r4) {
      e[r4] = (r4 + 4 * hi < W) ? __expf(0.125f * (sel[r4] - mx)) : 0.f;
      ls += e[r4];
    }
    ls += __shfl_xor(ls, 32);
    const float inv = 1.f / ls;

    unsigned dw0, dw1;
    CVTPK(dw0, e[0] * inv, e[1] * inv);
    CVTPK(dw1, e[2] * inv, e[3] * inv);
    const unsigned q0 = __shfl_xor(dw0, 32);
    const unsigned q1 = __shfl_xor(dw1, 32);

#pragma unroll
    for (int kh = 0; kh < 2; ++kh) {
      const bool on = (2 * kh + hi) == myb;
      u32x4 bw;
      if (hi == 0) { bw[0] = dw0; bw[1] = dw1; bw[2] = q0; bw[3] = q1; }
      else         { bw[0] = q0;  bw[1] = q1;  bw[2] = dw0; bw[3] = dw1; }
      if (!on) { bw[0] = 0u; bw[1] = 0u; bw[2] = 0u; bw[3] = 0u; }
      const bf16x8 pf = __builtin_bit_cast(bf16x8, bw);
#pragma unroll
      for (int dh = 0; dh < 2; ++dh) {
        const int d_ = dh * 32 + dl;
        const int off = (d_ * 128 + pg * 64 + kh * 32 + hi * 16) ^ ((d_ & 7) << 4);
        const bf16x8 va =
            __builtin_bit_cast(bf16x8, *(const u32x4*)((const char*)L + off));
        accP[pg][dh] = __builtin_amdgcn_mfma_f32_32x32x16_bf16(va, pf, accP[pg][dh], 0, 0, 0);
      }
    }
  }

#pragma unroll
  for (int pg = 0; pg < 2; ++pg) {
    if ((dl & 7) < W) {
      const int m_o = (pg * 4 + (dl >> 3)) * W + (dl & 7);
#pragma unroll
      for (int dh = 0; dh < 2; ++dh) {
#pragma unroll
        for (int rq = 0; rq < 4; ++rq) {
          unsigned wa, wb;
          CVTPK(wa, accP[pg][dh][4 * rq + 0], accP[pg][dh][4 * rq + 1]);
          CVTPK(wb, accP[pg][dh][4 * rq + 2], accP[pg][dh][4 * rq + 3]);
          const int dwi = m_o * 34 + dh * 16 + rq * 4 + hi * 2;
          uint2 w; w.x = wa; w.y = wb;
          *(uint2*)(L + dwi) = w;
        }
      }
    }
  }
  asm volatile("s_waitcnt lgkmcnt(0)" ::: "memory");

  const int cho = lane >> 3, fb = lane & 7;
  float o[8] = {0.f, 0.f, 0.f, 0.f, 0.f, 0.f, 0.f, 0.f};
#pragma unroll
  for (int jj = 0; jj < W; ++jj) {
    const int mo = 8 * jj + cho;
    const uint2 w0 = *(const uint2*)(L + mo * 34 + fb * 4);
    const uint2 w1 = *(const uint2*)(L + mo * 34 + fb * 4 + 2);
    o[0] += bf2f((unsigned short)(w0.x & 0xffff));
    o[1] += bf2f((unsigned short)(w0.x >> 16));
    o[2] += bf2f((unsigned short)(w0.y & 0xffff));
    o[3] += bf2f((unsigned short)(w0.y >> 16));
    o[4] += bf2f((unsigned short)(w1.x & 0xffff));
    o[5] += bf2f((unsigned short)(w1.x >> 16));
    o[6] += bf2f((unsigned short)(w1.y & 0xffff));
    o[7] += bf2f((unsigned short)(w1.y >> 16));
  }
  const float invw = 1.f / (float)W;
  u16x8 ov;
#pragma unroll
  for (int e2 = 0; e2 < 8; ++e2) ov[e2] = f2bf(o[e2] * invw);
  *(u16x8*)(abar + ((size_t)bt << 9) + cho * 64 + fb * 8) = ov;
}

// =====================================================================
// Global attention — R7 proven version (52 us): MFMA flash 32x32x16,
// swapped operands, grid (8,64), dbuf V^T LDS, direct K/Q global loads.
// =====================================================================
__global__ __launch_bounds__(256)
void global_attn_mfma_kernel(const __hip_bfloat16* __restrict__ Xq,
                             const __hip_bfloat16* __restrict__ Xk,
                             const __hip_bfloat16* __restrict__ Xv,
                             __hip_bfloat16* __restrict__ att) {
  __shared__ unsigned vt[2][2048];
  const int tid = threadIdx.x;
  const int lane = tid & 63;
  const int wv = tid >> 6;
  const int qblk = blockIdx.x;
  const int bh = blockIdx.y;
  const size_t base = (size_t)bh << 16;
  const int c = lane & 31;
  const int g = lane >> 5;
  const int q0 = qblk * 128 + wv * 32;

  const __hip_bfloat16* Qp = Xq + base;
  const __hip_bfloat16* Kp = Xk + base;
  const __hip_bfloat16* Vp = Xv + base;

  bf16x8 qf[4];
#pragma unroll
  for (int s = 0; s < 4; ++s)
    qf[s] = *(const bf16x8*)(Qp + (size_t)(q0 + c) * 64 + s * 16 + g * 8);

  const int k2 = tid & 31, dblk = tid >> 5;

  bf16x8 kf[2][4];
  u16x8 v0, v1, v0n, v1n;

  v0 = *(const u16x8*)(Vp + (size_t)(2 * k2) * 64 + dblk * 8);
  v1 = *(const u16x8*)(Vp + (size_t)(2 * k2 + 1) * 64 + dblk * 8);
#pragma unroll
  for (int kb = 0; kb < 2; ++kb)
#pragma unroll
    for (int s = 0; s < 4; ++s)
      kf[kb][s] = *(const bf16x8*)(Kp + (size_t)(kb * 32 + c) * 64 + s * 16 + g * 8);

  f32x16 Oa = (f32x16)(0.0f), Ob = (f32x16)(0.0f);
  float m_run = -3e38f, l_run = 0.f;

  for (int kt = 0; kt < 16; ++kt) {
    unsigned* vb = &vt[kt & 1][0];
#pragma unroll
    for (int jj = 0; jj < 8; ++jj) {
      const int d = dblk * 8 + jj;
      const unsigned dw = (unsigned)v0[jj] | ((unsigned)v1[jj] << 16);
      const int byte = (d * 128 + k2 * 4) ^ ((d & 7) << 4);
      vb[byte >> 2] = dw;
    }
    if (kt < 15) {
      const __hip_bfloat16* vsrc = Vp + (size_t)((kt + 1) * 64 + 2 * k2) * 64 + dblk * 8;
      v0n = *(const u16x8*)vsrc;
      v1n = *(const u16x8*)(vsrc + 64);
    }
    __syncthreads();

    f32x16 sa = (f32x16)(0.0f), sb = (f32x16)(0.0f);
#pragma unroll
    for (int s = 0; s < 4; ++s)
      sa = __builtin_amdgcn_mfma_f32_32x32x16_bf16(kf[0][s], qf[s], sa, 0, 0, 0);
#pragma unroll
    for (int s = 0; s < 4; ++s)
      sb = __builtin_amdgcn_mfma_f32_32x32x16_bf16(kf[1][s], qf[s], sb, 0, 0, 0);

    if (kt < 15) {
#pragma unroll
      for (int kb = 0; kb < 2; ++kb)
#pragma unroll
        for (int s = 0; s < 4; ++s)
          kf[kb][s] = *(const bf16x8*)(Kp + (size_t)((kt + 1) * 64 + kb * 32 + c) * 64 +
                                       s * 16 + g * 8);
    }

    float mx = sa[0];
#pragma unroll
    for (int r = 1; r < 16; ++r) mx = fmaxf(mx, sa[r]);
#pragma unroll
    for (int r = 0; r < 16; ++r) mx = fmaxf(mx, sb[r]);
    mx = fmaxf(mx, __shfl_xor(mx, 32));
    const float m_new = fmaxf(m_run, mx * 0.125f);
    const float alpha = __expf(m_run - m_new);

    float p0[16], p1[16];
    float lsum = 0.f;
#pragma unroll
    for (int r = 0; r < 16; ++r) { p0[r] = __expf(fmaf(sa[r], 0.125f, -m_new)); lsum += p0[r]; }
#pragma unroll
    for (int r = 0; r < 16; ++r) { p1[r] = __expf(fmaf(sb[r], 0.125f, -m_new)); lsum += p1[r]; }
    lsum += __shfl_xor(lsum, 32);
    l_run = fmaf(l_run, alpha, lsum);
    m_run = m_new;
#pragma unroll
    for (int r = 0; r < 16; ++r) { Oa[r] *= alpha; Ob[r] *= alpha; }

    unsigned bw[2][2][4];
#define REDIST(pb, kb_)                                                  \
    {                                                                    \
      unsigned t0_, t1_, t2_, t3_, t4_, t5_, t6_, t7_;                   \
      CVTPK(t0_, pb[0], pb[1]);   CVTPK(t1_, pb[2], pb[3]);              \
      CVTPK(t2_, pb[4], pb[5]);   CVTPK(t3_, pb[6], pb[7]);              \
      CVTPK(t4_, pb[8], pb[9]);   CVTPK(t5_, pb[10], pb[11]);            \
      CVTPK(t6_, pb[12], pb[13]); CVTPK(t7_, pb[14], pb[15]);            \
      swap32(t0_, t2_, lane); swap32(t1_, t3_, lane);                    \
      swap32(t4_, t6_, lane); swap32(t5_, t7_, lane);                    \
      bw[kb_][0][0] = t0_; bw[kb_][0][1] = t1_; bw[kb_][0][2] = t2_;     \
      bw[kb_][0][3] = t3_;                                               \
      bw[kb_][1][0] = t4_; bw[kb_][1][1] = t5_; bw[kb_][1][2] = t6_;     \
      bw[kb_][1][3] = t7_;                                               \
    }
    REDIST(p0, 0)
    REDIST(p1, 1)
#undef REDIST

    const unsigned* vbr = &vt[kt & 1][0];
#pragma unroll
    for (int kb = 0; kb < 2; ++kb)
#pragma unroll
      for (int st = 0; st < 2; ++st) {
        const u32x4 pw = { bw[kb][st][0], bw[kb][st][1], bw[kb][st][2], bw[kb][st][3] };
        const bf16x8 pf = __builtin_bit_cast(bf16x8, pw);
        {
          const int row = c;
          const int off = (row * 128 + (kb * 64 + st * 32 + g * 16)) ^ ((row & 7) << 4);
          const bf16x8 va = __builtin_bit_cast(bf16x8, *(const u32x4*)((const char*)vbr + off));
          Oa = __builtin_amdgcn_mfma_f32_32x32x16_bf16(va, pf, Oa, 0, 0, 0);
        }
        {
          const int row = 32 + c;
          const int off = (row * 128 + (kb * 64 + st * 32 + g * 16)) ^ ((row & 7) << 4);
          const bf16x8 va = __builtin_bit_cast(bf16x8, *(const u32x4*)((const char*)vbr + off));
          Ob = __builtin_amdgcn_mfma_f32_32x32x16_bf16(va, pf, Ob, 0, 0, 0);
        }
      }

    v0 = v0n; v1 = v1n;
  }

  const float inv = 1.f / l_run;
  __hip_bfloat16* drow = att + base + (size_t)(q0 + c) * 64;
#pragma unroll
  for (int qd = 0; qd < 4; ++qd) {
    unsigned lo, hi2;
    {
      const float a0 = Oa[4 * qd + 0] * inv, a1 = Oa[4 * qd + 1] * inv;
      const float a2 = Oa[4 * qd + 2] * inv, a3 = Oa[4 * qd + 3] * inv;
      CVTPK(lo, a0, a1); CVTPK(hi2, a2, a3);
      uint2 w; w.x = lo; w.y = hi2;
      *(uint2*)(drow + 8 * qd + 4 * g) = w;
    }
    {
      const float a0 = Ob[4 * qd + 0] * inv, a1 = Ob[4 * qd + 1] * inv;
      const float a2 = Ob[4 * qd + 2] * inv, a3 = Ob[4 * qd + 3] * inv;
      CVTPK(lo, a0, a1); CVTPK(hi2, a2, a3);
      uint2 w; w.x = lo; w.y = hi2;
      *(uint2*)(drow + 32 + 8 * qd + 4 * g) = w;
    }
  }
}

// =====================================================================
// Launch
// =====================================================================
extern "C" void kernel_launch(void* const* d_in, const int* in_sizes, int n_in,
                              void* d_out, int out_size, void* d_ws, size_t ws_size,
                              hipStream_t stream) {
  const float* x      = (const float*)d_in[0];
  const float* loc_wq = (const float*)d_in[1];
  const float* loc_bq = (const float*)d_in[2];
  const float* loc_wk = (const float*)d_in[3];
  const float* loc_bk = (const float*)d_in[4];
  const float* loc_wv = (const float*)d_in[5];
  const float* loc_bv = (const float*)d_in[6];
  const float* loc_wo = (const float*)d_in[7];
  const float* loc_bo = (const float*)d_in[8];
  const float* g_wq  = (const float*)d_in[9];
  const float* g_bq  = (const float*)d_in[10];
  const float* g_wk  = (const float*)d_in[11];
  const float* g_bk  = (const float*)d_in[12];
  const float* g_wv  = (const float*)d_in[13];
  const float* g_bv  = (const float*)d_in[14];
  const float* g_wo  = (const float*)d_in[15];
  const float* g_bo  = (const float*)d_in[16];
  const float* out_w = (const float*)d_in[17];
  const float* out_b = (const float*)d_in[18];
  float* out = (float*)d_out;

  __hip_bfloat16* wsb = (__hip_bfloat16*)d_ws;
  const size_t SZ = (size_t)8192 * 512;
  const size_t MS = (size_t)512 * 512;
  // WT slots: 0-8 loc qkv, 9-11 g qkv, 12-15 outw^T, 16-18 loc_wo (plain),
  //           19 g_wo (plain), 20-23 Wfused^T
  __hip_bfloat16* xb    = wsb;
  __hip_bfloat16* WT    = wsb + SZ;
  __hip_bfloat16* Xq    = wsb + SZ + 24 * MS;
  __hip_bfloat16* Xk    = Xq + SZ;
  __hip_bfloat16* Xv    = Xq + 2 * SZ;
  __hip_bfloat16* abar0 = Xq + 3 * SZ;
  __hip_bfloat16* abar1 = Xq + 4 * SZ;
  __hip_bfloat16* abar2 = Xq + 5 * SZ;
  __hip_bfloat16* abar3 = Xq + 6 * SZ;
  float* bfused = (float*)(Xq + 7 * SZ);                    // 4 x 512 fp32
  __hip_bfloat16* bqkvb = (__hip_bfloat16*)(bfused + 2048); // 9 x 512 bf16
  __hip_bfloat16* abars[3] = {abar0, abar1, abar2};

  const dim3 thr(256);

  // ---- one-time prep (3 dispatches) ----
  prep_weights_kernel<<<dim3(256, 22), thr, 0, stream>>>(
      loc_wq, loc_wk, loc_wv, g_wq, g_wk, g_wv, out_w, loc_wo, g_wo,
      x, loc_bq, loc_bk, loc_bv, WT, xb, bqkvb);
  gemm_fusew_kernel<<<dim3(4, 4, 4), thr, 0, stream>>>(WT + 12 * MS, WT + 16 * MS,
                                                       WT + 20 * MS);
  bias_fuse_kernel<<<dim3(2, 4), thr, 0, stream>>>(loc_bo, g_bo, out_w, out_b, bfused);

  const dim3 gqkv(4, 64, 3);

  for (int lv = 0; lv < 3; ++lv) {
    gemm_qkv_kernel<<<gqkv, thr, 0, stream>>>(
        xb, WT + lv * MS, 3 * MS,
        loc_bq + lv * 512, loc_bk + lv * 512, loc_bv + lv * 512, Xq);

    const __hip_bfloat16* bqb = bqkvb + (lv * 3 + 0) * 512;
    const __hip_bfloat16* bkb = bqkvb + (lv * 3 + 1) * 512;
    const __hip_bfloat16* bvb = bqkvb + (lv * 3 + 2) * 512;
    if (lv == 0)
      local_attn_mfma_kernel<3><<<2048, thr, 0, stream>>>(Xq, Xk, Xv, bqb, bkb, bvb, abars[lv]);
    else if (lv == 1)
      local_attn_mfma_kernel<5><<<2048, thr, 0, stream>>>(Xq, Xk, Xv, bqb, bkb, bvb, abars[lv]);
    else
      local_attn_mfma_kernel<7><<<2048, thr, 0, stream>>>(Xq, Xk, Xv, bqb, bkb, bvb, abars[lv]);
  }

  // global branch
  gemm_qkv_kernel<<<gqkv, thr, 0, stream>>>(xb, WT + 9 * MS, MS, g_bq, g_bk, g_bv, Xq);
  global_attn_mfma_kernel<<<dim3(8, 64), thr, 0, stream>>>(Xq, Xk, Xv, abar3);

  // fused output projection: one K=2048 GEMM (BM=64), out written once
  gemm_out_fused_kernel<<<dim3(4, 128), thr, 0, stream>>>(abar0, abar1, abar2, abar3,
                                                          WT + 20 * MS, bfused, out);
}

// Round 10
// 289.745 us; speedup vs baseline: 1.0700x; 1.0013x over previous
//
#include <hip/hip_runtime.h>
#include <hip/hip_bf16.h>
#include <cstddef>

#define T_SEQ 1024
#define D_MODEL 512

typedef __attribute__((ext_vector_type(8))) __bf16 bf16x8;
typedef __attribute__((ext_vector_type(4))) float f32x4;
typedef __attribute__((ext_vector_type(16))) float f32x16;
typedef __attribute__((ext_vector_type(8))) unsigned short u16x8;
typedef __attribute__((ext_vector_type(4))) unsigned int u32x4;

typedef const unsigned int __attribute__((address_space(1)))* gas1_t;
typedef unsigned int __attribute__((address_space(3)))* las3_t;

__device__ __forceinline__ void gload_lds16(const void* g, void* l) {
  __builtin_amdgcn_global_load_lds((gas1_t)g, (las3_t)l, 16, 0, 0);
}

__device__ __forceinline__ float bf2f(unsigned short u) {
  return __uint_as_float(((unsigned)u) << 16);
}
__device__ __forceinline__ unsigned short f2bf(float f) {
  __hip_bfloat16 h = __float2bfloat16(f);
  return *(unsigned short*)&h;
}

#define CVTPK(dst, a, b) \
  asm("v_cvt_pk_bf16_f32 %0, %1, %2" : "=v"(dst) : "v"(a), "v"(b))

// exchange lane halves between two dwords (global attn P redistribution)
__device__ __forceinline__ void swap32(unsigned& a, unsigned& b, int lane) {
  const unsigned ax = __shfl_xor(a, 32);
  const unsigned bx = __shfl_xor(b, 32);
  const bool lo = lane < 32;
  const unsigned na = lo ? a : bx;
  const unsigned nb = lo ? ax : b;
  a = na; b = nb;
}

// =====================================================================
// ALL prep in ONE dispatch. z = blockIdx.y:
//  0-2 loc_wq (T), 3-5 loc_wk (T), 6-8 loc_wv (T), 9 g_wq (T), 10 g_wk (T),
//  11 g_wv (T), 12-15 out_w (T), 16-18 loc_wo (cast), 19 g_wo (cast),
//  20 x fp32->bf16 cast, 21 q/k/v bias casts.
// =====================================================================
__global__ __launch_bounds__(256)
void prep_weights_kernel(const float* __restrict__ loc_wq, const float* __restrict__ loc_wk,
                         const float* __restrict__ loc_wv, const float* __restrict__ g_wq,
                         const float* __restrict__ g_wk, const float* __restrict__ g_wv,
                         const float* __restrict__ out_w, const float* __restrict__ loc_wo,
                         const float* __restrict__ g_wo, const float* __restrict__ x,
                         const float* __restrict__ loc_bq, const float* __restrict__ loc_bk,
                         const float* __restrict__ loc_bv,
                         __hip_bfloat16* __restrict__ WT, __hip_bfloat16* __restrict__ xb,
                         __hip_bfloat16* __restrict__ bqkvb) {
  __shared__ float tile[32][33];
  const size_t MS = (size_t)512 * 512;
  const int z = blockIdx.y;
  const int t = threadIdx.x;

  if (z == 20) {   // cast x
    const int base = blockIdx.x * 16384 + t * 8;
#pragma unroll
    for (int it = 0; it < 8; ++it) {
      const int i = base + it * 2048;
      const float4 a = *(const float4*)(x + i);
      const float4 b = *(const float4*)(x + i + 4);
      u16x8 o;
      o[0] = f2bf(a.x); o[1] = f2bf(a.y); o[2] = f2bf(a.z); o[3] = f2bf(a.w);
      o[4] = f2bf(b.x); o[5] = f2bf(b.y); o[6] = f2bf(b.z); o[7] = f2bf(b.w);
      *(u16x8*)(xb + i) = o;
    }
    return;
  }
  if (z == 21) {   // cast q/k/v biases
    const int i = blockIdx.x * 256 + t;
    if (blockIdx.x < 18) {
      const int which = i >> 9, lv = which / 3, role = which % 3, e = i & 511;
      const float* src = role == 0 ? loc_bq : role == 1 ? loc_bk : loc_bv;
      bqkvb[i] = __float2bfloat16(src[lv * 512 + e]);
    }
    return;
  }

  const float* src;
  bool tr = true;
  if (z < 3)       src = loc_wq + (size_t)z * MS;
  else if (z < 6)  src = loc_wk + (size_t)(z - 3) * MS;
  else if (z < 9)  src = loc_wv + (size_t)(z - 6) * MS;
  else if (z == 9)  src = g_wq;
  else if (z == 10) src = g_wk;
  else if (z == 11) src = g_wv;
  else if (z < 16) src = out_w + (size_t)(z - 12) * MS;
  else if (z < 19) { src = loc_wo + (size_t)(z - 16) * MS; tr = false; }
  else             { src = g_wo; tr = false; }
  __hip_bfloat16* dst = WT + (size_t)z * MS;

  const int tk = (blockIdx.x & 15) * 32;
  const int tn = (blockIdx.x >> 4) * 32;
  const int r = t >> 3, c4 = (t & 7) * 4;
  const float4 v = *(const float4*)(src + (size_t)(tk + r) * 512 + tn + c4);
  if (tr) {
    tile[r][c4 + 0] = v.x; tile[r][c4 + 1] = v.y;
    tile[r][c4 + 2] = v.z; tile[r][c4 + 3] = v.w;
    __syncthreads();
    ushort4 o;
    o.x = f2bf(tile[c4 + 0][r]); o.y = f2bf(tile[c4 + 1][r]);
    o.z = f2bf(tile[c4 + 2][r]); o.w = f2bf(tile[c4 + 3][r]);
    *(ushort4*)(dst + (size_t)(tn + r) * 512 + tk + c4) = o;
  } else {
    ushort4 o;
    o.x = f2bf(v.x); o.y = f2bf(v.y); o.z = f2bf(v.z); o.w = f2bf(v.w);
    *(ushort4*)(dst + (size_t)(tk + r) * 512 + tn + c4) = o;
  }
}

// =====================================================================
// Fused bias: bfused[z][n] = bo_z @ out_w[z*512..] (+ out_b for z==0).
// =====================================================================
__global__ __launch_bounds__(256)
void bias_fuse_kernel(const float* __restrict__ loc_bo, const float* __restrict__ g_bo,
                      const float* __restrict__ out_w, const float* __restrict__ out_b,
                      float* __restrict__ bfused) {
  const int z = blockIdx.y;
  const int n = blockIdx.x * 256 + threadIdx.x;
  const float* bo = (z < 3) ? loc_bo + z * 512 : g_bo;
  const float* W = out_w + (size_t)z * 512 * 512;
  float acc = (z == 0) ? out_b[n] : 0.f;
  for (int m = 0; m < 512; ++m)
    acc = fmaf(bo[m], W[(size_t)m * 512 + n], acc);
  bfused[z * 512 + n] = acc;
}

// =====================================================================
// MFMA GEMM cores (proven).
// =====================================================================
__device__ __forceinline__ void gemm_core_b128(
    const __hip_bfloat16* __restrict__ A, const __hip_bfloat16* __restrict__ BT,
    __hip_bfloat16* As, __hip_bfloat16* Bs, int row0, int col0, f32x4 acc[4][4]) {
  const int tid = threadIdx.x;
  const int wv = tid >> 6, lane = tid & 63;
  const int g = lane >> 4, r16 = lane & 15;
  const int wm = wv >> 1, wn = wv & 1;
  const char* Ab = (const char*)A;
  const char* Bb = (const char*)BT;
  for (int k0 = 0; k0 < 512; k0 += 32) {
    {
      const int row = tid >> 2, off = (tid & 3) << 4;
      gload_lds16(Ab + (size_t)(row0 + row) * 1024 + k0 * 2 + off,
                  (char*)As + (wv << 10));
      const int i2 = tid + 256;
      const int row2 = i2 >> 2, off2 = (i2 & 3) << 4;
      gload_lds16(Ab + (size_t)(row0 + row2) * 1024 + k0 * 2 + off2,
                  (char*)As + 4096 + (wv << 10));
    }
    {
      const int row = tid >> 2, off = (tid & 3) << 4;
      gload_lds16(Bb + (size_t)(col0 + row) * 1024 + k0 * 2 + off,
                  (char*)Bs + (wv << 10));
      const int i2 = tid + 256;
      const int row2 = i2 >> 2, off2 = (i2 & 3) << 4;
      gload_lds16(Bb + (size_t)(col0 + row2) * 1024 + k0 * 2 + off2,
                  (char*)Bs + 4096 + (wv << 10));
    }
    __syncthreads();
    bf16x8 a[4], b[4];
#pragma unroll
    for (int m = 0; m < 4; ++m)
      a[m] = *(const bf16x8*)(As + (wm * 64 + m * 16 + r16) * 32 + g * 8);
#pragma unroll
    for (int n = 0; n < 4; ++n)
      b[n] = *(const bf16x8*)(Bs + (wn * 64 + n * 16 + r16) * 32 + g * 8);
#pragma unroll
    for (int m = 0; m < 4; ++m)
#pragma unroll
      for (int n = 0; n < 4; ++n)
        acc[m][n] = __builtin_amdgcn_mfma_f32_16x16x32_bf16(a[m], b[n], acc[m][n], 0, 0, 0);
    __syncthreads();
  }
}

__device__ __forceinline__ void gemm_core_b64(
    const __hip_bfloat16* __restrict__ A, const __hip_bfloat16* __restrict__ BT,
    __hip_bfloat16* As, __hip_bfloat16* Bs, int row0, int col0, f32x4 acc[2][4]) {
  const int tid = threadIdx.x;
  const int wv = tid >> 6, lane = tid & 63;
  const int g = lane >> 4, r16 = lane & 15;
  const int wm = wv >> 1, wn = wv & 1;
  const char* Ab = (const char*)A;
  const char* Bb = (const char*)BT;
  for (int k0 = 0; k0 < 512; k0 += 32) {
    {
      const int row = tid >> 2, off = (tid & 3) << 4;
      gload_lds16(Ab + (size_t)(row0 + row) * 1024 + k0 * 2 + off,
                  (char*)As + (wv << 10));
    }
    {
      const int row = tid >> 2, off = (tid & 3) << 4;
      gload_lds16(Bb + (size_t)(col0 + row) * 1024 + k0 * 2 + off,
                  (char*)Bs + (wv << 10));
      const int i2 = tid + 256;
      const int row2 = i2 >> 2, off2 = (i2 & 3) << 4;
      gload_lds16(Bb + (size_t)(col0 + row2) * 1024 + k0 * 2 + off2,
                  (char*)Bs + 4096 + (wv << 10));
    }
    __syncthreads();
    bf16x8 a[2], b[4];
#pragma unroll
    for (int m = 0; m < 2; ++m)
      a[m] = *(const bf16x8*)(As + (wm * 32 + m * 16 + r16) * 32 + g * 8);
#pragma unroll
    for (int n = 0; n < 4; ++n)
      b[n] = *(const bf16x8*)(Bs + (wn * 64 + n * 16 + r16) * 32 + g * 8);
#pragma unroll
    for (int m = 0; m < 2; ++m)
#pragma unroll
      for (int n = 0; n < 4; ++n)
        acc[m][n] = __builtin_amdgcn_mfma_f32_16x16x32_bf16(a[m], b[n], acc[m][n], 0, 0, 0);
    __syncthreads();
  }
}

// Fallback per-level Q/K/V projection (3 z-slices into shared buffers).
__global__ __launch_bounds__(256)
void gemm_qkv_kernel(const __hip_bfloat16* __restrict__ A,
                     const __hip_bfloat16* __restrict__ WT_base, size_t wt_stride,
                     const float* __restrict__ b0, const float* __restrict__ b1,
                     const float* __restrict__ b2,
                     __hip_bfloat16* __restrict__ out_base) {
  __shared__ __attribute__((aligned(16))) __hip_bfloat16 As[4096];
  __shared__ __attribute__((aligned(16))) __hip_bfloat16 Bs[4096];
  const int z = blockIdx.z;
  const __hip_bfloat16* WT = WT_base + (size_t)z * wt_stride;
  const float* bias = (z == 0) ? b0 : (z == 1) ? b1 : b2;
  __hip_bfloat16* C = out_base + (size_t)z * (size_t)(8192 * 512);
  const int row0 = blockIdx.y * 128, col0 = blockIdx.x * 128;
  f32x4 acc[4][4];
#pragma unroll
  for (int m = 0; m < 4; ++m)
#pragma unroll
    for (int n = 0; n < 4; ++n) acc[m][n] = (f32x4)(0.0f);
  gemm_core_b128(A, WT, As, Bs, row0, col0, acc);
  const int lane = threadIdx.x & 63, wv = threadIdx.x >> 6;
  const int g = lane >> 4, r16 = lane & 15, wm = wv >> 1, wn = wv & 1;
#pragma unroll
  for (int n = 0; n < 4; ++n) {
    const int col = col0 + wn * 64 + n * 16 + r16;
    const float bn = bias[col];
#pragma unroll
    for (int m = 0; m < 4; ++m) {
      const int rowb = row0 + wm * 64 + m * 16 + g * 4;
#pragma unroll
      for (int r = 0; r < 4; ++r)
        C[(size_t)(rowb + r) * 512 + col] = __float2bfloat16(acc[m][n][r] + bn);
    }
  }
}

// Mega Q/K/V: ALL 12 projections in one dispatch (z = 0..11 matches WT
// slots 0..11), each to its own buffer proj + z*SZ.
__global__ __launch_bounds__(256)
void gemm_qkv_all_kernel(const __hip_bfloat16* __restrict__ A,
                         const __hip_bfloat16* __restrict__ WT_base,
                         const float* __restrict__ loc_bq, const float* __restrict__ loc_bk,
                         const float* __restrict__ loc_bv, const float* __restrict__ g_bq,
                         const float* __restrict__ g_bk, const float* __restrict__ g_bv,
                         __hip_bfloat16* __restrict__ proj_base) {
  __shared__ __attribute__((aligned(16))) __hip_bfloat16 As[4096];
  __shared__ __attribute__((aligned(16))) __hip_bfloat16 Bs[4096];
  const size_t MS = (size_t)512 * 512;
  const int z = blockIdx.z;
  const __hip_bfloat16* WT = WT_base + (size_t)z * MS;
  const float* bias;
  if (z < 3)       bias = loc_bq + z * 512;
  else if (z < 6)  bias = loc_bk + (z - 3) * 512;
  else if (z < 9)  bias = loc_bv + (z - 6) * 512;
  else             bias = (z == 9) ? g_bq : (z == 10) ? g_bk : g_bv;
  __hip_bfloat16* C = proj_base + (size_t)z * (size_t)(8192 * 512);
  const int row0 = blockIdx.y * 128, col0 = blockIdx.x * 128;
  f32x4 acc[4][4];
#pragma unroll
  for (int m = 0; m < 4; ++m)
#pragma unroll
    for (int n = 0; n < 4; ++n) acc[m][n] = (f32x4)(0.0f);
  gemm_core_b128(A, WT, As, Bs, row0, col0, acc);
  const int lane = threadIdx.x & 63, wv = threadIdx.x >> 6;
  const int g = lane >> 4, r16 = lane & 15, wm = wv >> 1, wn = wv & 1;
#pragma unroll
  for (int n = 0; n < 4; ++n) {
    const int col = col0 + wn * 64 + n * 16 + r16;
    const float bn = bias[col];
#pragma unroll
    for (int m = 0; m < 4; ++m) {
      const int rowb = row0 + wm * 64 + m * 16 + g * 4;
#pragma unroll
      for (int r = 0; r < 4; ++r)
        C[(size_t)(rowb + r) * 512 + col] = __float2bfloat16(acc[m][n][r] + bn);
    }
  }
}

// Fused-weight GEMM: WfT[z] = (wo_z @ outw_z)^T (BM=128, batched z).
__global__ __launch_bounds__(256)
void gemm_fusew_kernel(const __hip_bfloat16* __restrict__ A_base,
                       const __hip_bfloat16* __restrict__ BT_base,
                       __hip_bfloat16* __restrict__ C_base) {
  __shared__ __attribute__((aligned(16))) __hip_bfloat16 As[4096];
  __shared__ __attribute__((aligned(16))) __hip_bfloat16 Bs[4096];
  const size_t MS = (size_t)512 * 512;
  const int z = blockIdx.z;
  const __hip_bfloat16* A = A_base + z * MS;
  const __hip_bfloat16* BT = BT_base + z * MS;
  __hip_bfloat16* C = C_base + z * MS;
  const int row0 = blockIdx.y * 128, col0 = blockIdx.x * 128;
  f32x4 acc[4][4];
#pragma unroll
  for (int m = 0; m < 4; ++m)
#pragma unroll
    for (int n = 0; n < 4; ++n) acc[m][n] = (f32x4)(0.0f);
  gemm_core_b128(A, BT, As, Bs, row0, col0, acc);
  const int lane = threadIdx.x & 63, wv = threadIdx.x >> 6;
  const int g = lane >> 4, r16 = lane & 15, wm = wv >> 1, wn = wv & 1;
#pragma unroll
  for (int n = 0; n < 4; ++n) {
    const int col = col0 + wn * 64 + n * 16 + r16;
#pragma unroll
    for (int m = 0; m < 4; ++m) {
      const int rowb = row0 + wm * 64 + m * 16 + g * 4;
#pragma unroll
      for (int r = 0; r < 4; ++r)
        C[(size_t)(rowb + r) * 512 + col] = __float2bfloat16(acc[m][n][r]);
    }
  }
}

// Final fused output GEMM (BM=64, grid (4,128)):
__global__ __launch_bounds__(256)
void gemm_out_fused_kernel(const __hip_bfloat16* __restrict__ A0,
                           const __hip_bfloat16* __restrict__ A1,
                           const __hip_bfloat16* __restrict__ A2,
                           const __hip_bfloat16* __restrict__ A3,
                           const __hip_bfloat16* __restrict__ WT_base,
                           const float* __restrict__ bfused,
                           float* __restrict__ out) {
  __shared__ __attribute__((aligned(16))) __hip_bfloat16 As[2048];
  __shared__ __attribute__((aligned(16))) __hip_bfloat16 Bs[4096];
  const size_t MS = (size_t)512 * 512;
  const int row0 = blockIdx.y * 64, col0 = blockIdx.x * 128;
  f32x4 acc[2][4];
#pragma unroll
  for (int m = 0; m < 2; ++m)
#pragma unroll
    for (int n = 0; n < 4; ++n) acc[m][n] = (f32x4)(0.0f);
  const __hip_bfloat16* Az[4] = {A0, A1, A2, A3};
  for (int z = 0; z < 4; ++z)
    gemm_core_b64(Az[z], WT_base + (size_t)z * MS, As, Bs, row0, col0, acc);
  const int lane = threadIdx.x & 63, wv = threadIdx.x >> 6;
  const int g = lane >> 4, r16 = lane & 15, wm = wv >> 1, wn = wv & 1;
#pragma unroll
  for (int n = 0; n < 4; ++n) {
    const int col = col0 + wn * 64 + n * 16 + r16;
    const float bn = bfused[col] + bfused[512 + col] + bfused[1024 + col] +
                     bfused[1536 + col];
#pragma unroll
    for (int m = 0; m < 2; ++m) {
      const int rowb = row0 + wm * 32 + m * 16 + g * 4;
#pragma unroll
      for (int r = 0; r < 4; ++r)
        out[(size_t)(rowb + r) * 512 + col] = acc[m][n][r] + bn;
    }
  }
}

// =====================================================================
// Local windowed attention — MFMA, one wave per (b,t). (proven, R7)
// + T5 setprio around MFMA clusters.
// =====================================================================
template <int W>
__device__ __forceinline__ const __hip_bfloat16* slot_row(
    const __hip_bfloat16* __restrict__ X, const __hip_bfloat16* __restrict__ biasb,
    int b, int tloc, int pg, int sl, int* ch_out) {
  constexpr int PAD = (W - 1) / 2;
  const int hloc = sl >> 3, p = sl & 7;
  const int m = (pg * 4 + hloc) * W + p;
  const int j = m >> 3;
  *ch_out = m & 7;
  int sr = tloc + j - PAD;
  if (p < W) {
    if (sr >= 0 && sr < T_SEQ) return X + ((size_t)(b * T_SEQ + sr) << 9);
    return biasb;
  }
  sr = sr < 0 ? 0 : (sr > T_SEQ - 1 ? T_SEQ - 1 : sr);
  return X + ((size_t)(b * T_SEQ + sr) << 9);
}

template <int W>
__global__ __launch_bounds__(256)
void local_attn_mfma_kernel(const __hip_bfloat16* __restrict__ Xq,
                            const __hip_bfloat16* __restrict__ Xk,
                            const __hip_bfloat16* __restrict__ Xv,
                            const __hip_bfloat16* __restrict__ bqb,
                            const __hip_bfloat16* __restrict__ bkb,
                            const __hip_bfloat16* __restrict__ bvb,
                            __hip_bfloat16* __restrict__ abar) {
  __shared__ unsigned lds_u[4][2048];
  const int tid = threadIdx.x;
  const int wv = tid >> 6, lane = tid & 63;
  const int bt = blockIdx.x * 4 + wv;
  const int b = bt >> 10, tloc = bt & 1023;
  unsigned* L = &lds_u[wv][0];
  const int dl = lane & 31, hi = lane >> 5;

  {
    const int k2 = dl, dhalf = hi;
    int ch0, ch1;
    const __hip_bfloat16* r0 =
        slot_row<W>(Xv, bvb, b, tloc, (2 * k2) >> 5, (2 * k2) & 31, &ch0);
    const __hip_bfloat16* r1 =
        slot_row<W>(Xv, bvb, b, tloc, (2 * k2 + 1) >> 5, (2 * k2 + 1) & 31, &ch1);
    u16x8 A0[4], A1[4];
#pragma unroll
    for (int q = 0; q < 4; ++q) {
      A0[q] = *(const u16x8*)(r0 + ch0 * 64 + dhalf * 32 + q * 8);
      A1[q] = *(const u16x8*)(r1 + ch1 * 64 + dhalf * 32 + q * 8);
    }
#pragma unroll
    for (int q = 0; q < 4; ++q)
#pragma unroll
      for (int e = 0; e < 8; ++e) {
        const int d_ = dhalf * 32 + q * 8 + e;
        const unsigned dw = (unsigned)A0[q][e] | ((unsigned)A1[q][e] << 16);
        const int byte = (d_ * 128 + k2 * 4) ^ ((d_ & 7) << 4);
        L[byte >> 2] = dw;
      }
  }

  f32x16 accP[2][2];
#pragma unroll
  for (int pg = 0; pg < 2; ++pg)
#pragma unroll
    for (int dh = 0; dh < 2; ++dh) accP[pg][dh] = (f32x16)(0.0f);

  const int myb = dl >> 3;

#pragma unroll
  for (int pg = 0; pg < 2; ++pg) {
    int chK, chQ;
    const __hip_bfloat16* rK = slot_row<W>(Xk, bkb, b, tloc, pg, dl, &chK);
    const __hip_bfloat16* rQ = slot_row<W>(Xq, bqb, b, tloc, pg, dl, &chQ);
    f32x16 sa = (f32x16)(0.0f);
    __builtin_amdgcn_s_setprio(1);
#pragma unroll
    for (int i = 0; i < 4; ++i) {
      const bf16x8 kf = *(const bf16x8*)(rK + chK * 64 + i * 16 + hi * 8);
      const bf16x8 qf = *(const bf16x8*)(rQ + chQ * 64 + i * 16 + hi * 8);
      sa = __builtin_amdgcn_mfma_f32_32x32x16_bf16(kf, qf, sa, 0, 0, 0);
    }
    __builtin_amdgcn_s_setprio(0);

    float sel[4];
#pragma unroll
    for (int r4 = 0; r4 < 4; ++r4)
      sel[r4] = (myb == 0) ? sa[r4]
              : (myb == 1) ? sa[4 + r4]
              : (myb == 2) ? sa[8 + r4] : sa[12 + r4];

    float mx = -3e38f;
#pragma unroll
    for (int r4 = 0; r4 < 4; ++r4)
      if (r4 + 4 * hi < W) mx = fmaxf(mx, sel[r4]);
    mx = fmaxf(mx, __shfl_xor(mx, 32));
    float e[4], ls = 0.f;
#pragma unroll
    for (int r4 = 0; r4 < 4; ++r4) {
      e[r4] = (r4 + 4 * hi < W) ? __expf(0.125f * (sel[r4] - mx)) : 0.f;
      ls += e[r4];
    }
    ls += __shfl_xor(ls, 32);
    const float inv = 1.f / ls;

    unsigned dw0, dw1;
    CVTPK(dw0, e[0] * inv, e[1] * inv);
    CVTPK(dw1, e[2] * inv, e[3] * inv);
    const unsigned q0 = __shfl_xor(dw0, 32);
    const unsigned q1 = __shfl_xor(dw1, 32);

    __builtin_amdgcn_s_setprio(1);
#pragma unroll
    for (int kh = 0; kh < 2; ++kh) {
      const bool on = (2 * kh + hi) == myb;
      u32x4 bw;
      if (hi == 0) { bw[0] = dw0; bw[1] = dw1; bw[2] = q0; bw[3] = q1; }
      else         { bw[0] = q0;  bw[1] = q1;  bw[2] = dw0; bw[3] = dw1; }
      if (!on) { bw[0] = 0u; bw[1] = 0u; bw[2] = 0u; bw[3] = 0u; }
      const bf16x8 pf = __builtin_bit_cast(bf16x8, bw);
#pragma unroll
      for (int dh = 0; dh < 2; ++dh) {
        const int d_ = dh * 32 + dl;
        const int off = (d_ * 128 + pg * 64 + kh * 32 + hi * 16) ^ ((d_ & 7) << 4);
        const bf16x8 va =
            __builtin_bit_cast(bf16x8, *(const u32x4*)((const char*)L + off));
        accP[pg][dh] = __builtin_amdgcn_mfma_f32_32x32x16_bf16(va, pf, accP[pg][dh], 0, 0, 0);
      }
    }
    __builtin_amdgcn_s_setprio(0);
  }

#pragma unroll
  for (int pg = 0; pg < 2; ++pg) {
    if ((dl & 7) < W) {
      const int m_o = (pg * 4 + (dl >> 3)) * W + (dl & 7);
#pragma unroll
      for (int dh = 0; dh < 2; ++dh) {
#pragma unroll
        for (int rq = 0; rq < 4; ++rq) {
          unsigned wa, wb;
          CVTPK(wa, accP[pg][dh][4 * rq + 0], accP[pg][dh][4 * rq + 1]);
          CVTPK(wb, accP[pg][dh][4 * rq + 2], accP[pg][dh][4 * rq + 3]);
          const int dwi = m_o * 34 + dh * 16 + rq * 4 + hi * 2;
          uint2 w; w.x = wa; w.y = wb;
          *(uint2*)(L + dwi) = w;
        }
      }
    }
  }
  asm volatile("s_waitcnt lgkmcnt(0)" ::: "memory");

  const int cho = lane >> 3, fb = lane & 7;
  float o[8] = {0.f, 0.f, 0.f, 0.f, 0.f, 0.f, 0.f, 0.f};
#pragma unroll
  for (int jj = 0; jj < W; ++jj) {
    const int mo = 8 * jj + cho;
    const uint2 w0 = *(const uint2*)(L + mo * 34 + fb * 4);
    const uint2 w1 = *(const uint2*)(L + mo * 34 + fb * 4 + 2);
    o[0] += bf2f((unsigned short)(w0.x & 0xffff));
    o[1] += bf2f((unsigned short)(w0.x >> 16));
    o[2] += bf2f((unsigned short)(w0.y & 0xffff));
    o[3] += bf2f((unsigned short)(w0.y >> 16));
    o[4] += bf2f((unsigned short)(w1.x & 0xffff));
    o[5] += bf2f((unsigned short)(w1.x >> 16));
    o[6] += bf2f((unsigned short)(w1.y & 0xffff));
    o[7] += bf2f((unsigned short)(w1.y >> 16));
  }
  const float invw = 1.f / (float)W;
  u16x8 ov;
#pragma unroll
  for (int e2 = 0; e2 < 8; ++e2) ov[e2] = f2bf(o[e2] * invw);
  *(u16x8*)(abar + ((size_t)bt << 9) + cho * 64 + fb * 8) = ov;
}

// =====================================================================
// Global attention v3: R7 structure with KVBLK=128 (two 64-tiles per
// barrier, processed sequentially; halves barrier count 16 -> 8),
// exact defer-rescale (skip O-rescale when no column max grows), and
// T5 setprio around MFMA clusters.
// =====================================================================
#define REDIST(pb, kb_)                                                  \
    {                                                                    \
      unsigned t0_, t1_, t2_, t3_, t4_, t5_, t6_, t7_;                   \
      CVTPK(t0_, pb[0], pb[1]);   CVTPK(t1_, pb[2], pb[3]);              \
      CVTPK(t2_, pb[4], pb[5]);   CVTPK(t3_, pb[6], pb[7]);              \
      CVTPK(t4_, pb[8], pb[9]);   CVTPK(t5_, pb[10], pb[11]);            \
      CVTPK(t6_, pb[12], pb[13]); CVTPK(t7_, pb[14], pb[15]);            \
      swap32(t0_, t2_, lane); swap32(t1_, t3_, lane);                    \
      swap32(t4_, t6_, lane); swap32(t5_, t7_, lane);                    \
      bw[kb_][0][0] = t0_; bw[kb_][0][1] = t1_; bw[kb_][0][2] = t2_;     \
      bw[kb_][0][3] = t3_;                                               \
      bw[kb_][1][0] = t4_; bw[kb_][1][1] = t5_; bw[kb_][1][2] = t6_;     \
      bw[kb_][1][3] = t7_;                                               \
    }

#define SUBSTEP(KF, SUB)                                                        \
  {                                                                             \
    f32x16 sa = (f32x16)(0.0f), sb = (f32x16)(0.0f);                            \
    __builtin_amdgcn_s_setprio(1);                                              \
    _Pragma("unroll")                                                           \
    for (int s = 0; s < 4; ++s)                                                 \
      sa = __builtin_amdgcn_mfma_f32_32x32x16_bf16(KF[0][s], qf[s], sa, 0, 0, 0);\
    _Pragma("unroll")                                                           \
    for (int s = 0; s < 4; ++s)                                                 \
      sb = __builtin_amdgcn_mfma_f32_32x32x16_bf16(KF[1][s], qf[s], sb, 0, 0, 0);\
    __builtin_amdgcn_s_setprio(0);                                              \
    const int ktn = 2 * it + (SUB) + 2;                                         \
    if (ktn < 16) {                                                             \
      _Pragma("unroll")                                                         \
      for (int kb = 0; kb < 2; ++kb)                                            \
        _Pragma("unroll")                                                       \
        for (int s = 0; s < 4; ++s)                                             \
          KF[kb][s] = *(const bf16x8*)(Kp + (size_t)(ktn * 64 + kb * 32 + c) * 64 + \
                                       s * 16 + g * 8);                         \
    }                                                                           \
    float mx = sa[0];                                                           \
    _Pragma("unroll")                                                           \
    for (int r = 1; r < 16; ++r) mx = fmaxf(mx, sa[r]);                         \
    _Pragma("unroll")                                                           \
    for (int r = 0; r < 16; ++r) mx = fmaxf(mx, sb[r]);                         \
    mx = fmaxf(mx, __shfl_xor(mx, 32));                                         \
    const float mt = mx * 0.125f;                                               \
    if (__any(mt > m_run)) {                                                    \
      const float m_new = fmaxf(m_run, mt);                                     \
      const float alpha = __expf(m_run - m_new);                                \
      m_run = m_new;                                                            \
      l_run *= alpha;                                                           \
      _Pragma("unroll")                                                         \
      for (int r = 0; r < 16; ++r) { Oa[r] *= alpha; Ob[r] *= alpha; }          \
    }                                                                           \
    float p0[16], p1[16];                                                       \
    float lsum = 0.f;                                                           \
    _Pragma("unroll")                                                           \
    for (int r = 0; r < 16; ++r) { p0[r] = __expf(fmaf(sa[r], 0.125f, -m_run)); lsum += p0[r]; } \
    _Pragma("unroll")                                                           \
    for (int r = 0; r < 16; ++r) { p1[r] = __expf(fmaf(sb[r], 0.125f, -m_run)); lsum += p1[r]; } \
    lsum += __shfl_xor(lsum, 32);                                               \
    l_run += lsum;                                                              \
    unsigned bw[2][2][4];                                                       \
    REDIST(p0, 0)                                                               \
    REDIST(p1, 1)                                                               \
    const unsigned* vbr = &vt[it & 1][(SUB)][0];                                \
    __builtin_amdgcn_s_setprio(1);                                              \
    _Pragma("unroll")                                                           \
    for (int kb = 0; kb < 2; ++kb)                                              \
      _Pragma("unroll")                                                         \
      for (int st = 0; st < 2; ++st) {                                          \
        const u32x4 pw = { bw[kb][st][0], bw[kb][st][1], bw[kb][st][2], bw[kb][st][3] }; \
        const bf16x8 pf = __builtin_bit_cast(bf16x8, pw);                       \
        {                                                                       \
          const int row = c;                                                    \
          const int off = (row * 128 + (kb * 64 + st * 32 + g * 16)) ^ ((row & 7) << 4); \
          const bf16x8 va = __builtin_bit_cast(bf16x8, *(const u32x4*)((const char*)vbr + off)); \
          Oa = __builtin_amdgcn_mfma_f32_32x32x16_bf16(va, pf, Oa, 0, 0, 0);    \
        }                                                                       \
        {                                                                       \
          const int row = 32 + c;                                               \
          const int off = (row * 128 + (kb * 64 + st * 32 + g * 16)) ^ ((row & 7) << 4); \
          const bf16x8 va = __builtin_bit_cast(bf16x8, *(const u32x4*)((const char*)vbr + off)); \
          Ob = __builtin_amdgcn_mfma_f32_32x32x16_bf16(va, pf, Ob, 0, 0, 0);    \
        }                                                                       \
      }                                                                         \
    __builtin_amdgcn_s_setprio(0);                                              \
  }

__global__ __launch_bounds__(256)
void global_attn_mfma_kernel(const __hip_bfloat16* __restrict__ Xq,
                             const __hip_bfloat16* __restrict__ Xk,
                             const __hip_bfloat16* __restrict__ Xv,
                             __hip_bfloat16* __restrict__ att) {
  __shared__ unsigned vt[2][2][2048];   // [buf][sub-tile][8KB]
  const int tid = threadIdx.x;
  const int lane = tid & 63;
  const int wv = tid >> 6;
  const int qblk = blockIdx.x;
  const int bh = blockIdx.y;
  const size_t base = (size_t)bh << 16;
  const int c = lane & 31;
  const int g = lane >> 5;
  const int q0 = qblk * 128 + wv * 32;

  const __hip_bfloat16* Qp = Xq + base;
  const __hip_bfloat16* Kp = Xk + base;
  const __hip_bfloat16* Vp = Xv + base;

  bf16x8 qf[4];
#pragma unroll
  for (int s = 0; s < 4; ++s)
    qf[s] = *(const bf16x8*)(Qp + (size_t)(q0 + c) * 64 + s * 16 + g * 8);

  const int k2 = tid & 31, dblk = tid >> 5;

  bf16x8 kfA[2][4], kfB[2][4];
  u16x8 vA0, vA1, vB0, vB1;

  // prologue: V tiles 0 and 1; K tiles 0 and 1
  vA0 = *(const u16x8*)(Vp + (size_t)(2 * k2) * 64 + dblk * 8);
  vA1 = *(const u16x8*)(Vp + (size_t)(2 * k2 + 1) * 64 + dblk * 8);
  vB0 = *(const u16x8*)(Vp + (size_t)(64 + 2 * k2) * 64 + dblk * 8);
  vB1 = *(const u16x8*)(Vp + (size_t)(64 + 2 * k2 + 1) * 64 + dblk * 8);
#pragma unroll
  for (int kb = 0; kb < 2; ++kb)
#pragma unroll
    for (int s = 0; s < 4; ++s) {
      kfA[kb][s] = *(const bf16x8*)(Kp + (size_t)(kb * 32 + c) * 64 + s * 16 + g * 8);
      kfB[kb][s] = *(const bf16x8*)(Kp + (size_t)(64 + kb * 32 + c) * 64 + s * 16 + g * 8);
    }

  f32x16 Oa = (f32x16)(0.0f), Ob = (f32x16)(0.0f);
  float m_run = -3e38f, l_run = 0.f;

  for (int it = 0; it < 8; ++it) {
    // stage V tiles 2it and 2it+1 into vt[it&1][0/1]
    unsigned* vb0 = &vt[it & 1][0][0];
    unsigned* vb1 = &vt[it & 1][1][0];
#pragma unroll
    for (int jj = 0; jj < 8; ++jj) {
      const int d = dblk * 8 + jj;
      const int byte = (d * 128 + k2 * 4) ^ ((d & 7) << 4);
      vb0[byte >> 2] = (unsigned)vA0[jj] | ((unsigned)vA1[jj] << 16);
      vb1[byte >> 2] = (unsigned)vB0[jj] | ((unsigned)vB1[jj] << 16);
    }
    if (it < 7) {
      const __hip_bfloat16* sA = Vp + (size_t)((2 * it + 2) * 64 + 2 * k2) * 64 + dblk * 8;
      vA0 = *(const u16x8*)sA;
      vA1 = *(const u16x8*)(sA + 64);
      const __hip_bfloat16* sB = Vp + (size_t)((2 * it + 3) * 64 + 2 * k2) * 64 + dblk * 8;
      vB0 = *(const u16x8*)sB;
      vB1 = *(const u16x8*)(sB + 64);
    }
    __syncthreads();

    SUBSTEP(kfA, 0)
    SUBSTEP(kfB, 1)
  }

  const float inv = 1.f / l_run;
  __hip_bfloat16* drow = att + base + (size_t)(q0 + c) * 64;
#pragma unroll
  for (int qd = 0; qd < 4; ++qd) {
    unsigned lo, hi2;
    {
      const float a0 = Oa[4 * qd + 0] * inv, a1 = Oa[4 * qd + 1] * inv;
      const float a2 = Oa[4 * qd + 2] * inv, a3 = Oa[4 * qd + 3] * inv;
      CVTPK(lo, a0, a1); CVTPK(hi2, a2, a3);
      uint2 w; w.x = lo; w.y = hi2;
      *(uint2*)(drow + 8 * qd + 4 * g) = w;
    }
    {
      const float a0 = Ob[4 * qd + 0] * inv, a1 = Ob[4 * qd + 1] * inv;
      const float a2 = Ob[4 * qd + 2] * inv, a3 = Ob[4 * qd + 3] * inv;
      CVTPK(lo, a0, a1); CVTPK(hi2, a2, a3);
      uint2 w; w.x = lo; w.y = hi2;
      *(uint2*)(drow + 32 + 8 * qd + 4 * g) = w;
    }
  }
}

// =====================================================================
// Launch
// =====================================================================
extern "C" void kernel_launch(void* const* d_in, const int* in_sizes, int n_in,
                              void* d_out, int out_size, void* d_ws, size_t ws_size,
                              hipStream_t stream) {
  const float* x      = (const float*)d_in[0];
  const float* loc_wq = (const float*)d_in[1];
  const float* loc_bq = (const float*)d_in[2];
  const float* loc_wk = (const float*)d_in[3];
  const float* loc_bk = (const float*)d_in[4];
  const float* loc_wv = (const float*)d_in[5];
  const float* loc_bv = (const float*)d_in[6];
  const float* loc_wo = (const float*)d_in[7];
  const float* loc_bo = (const float*)d_in[8];
  const float* g_wq  = (const float*)d_in[9];
  const float* g_bq  = (const float*)d_in[10];
  const float* g_wk  = (const float*)d_in[11];
  const float* g_bk  = (const float*)d_in[12];
  const float* g_wv  = (const float*)d_in[13];
  const float* g_bv  = (const float*)d_in[14];
  const float* g_wo  = (const float*)d_in[15];
  const float* g_bo  = (const float*)d_in[16];
  const float* out_w = (const float*)d_in[17];
  const float* out_b = (const float*)d_in[18];
  float* out = (float*)d_out;

  __hip_bfloat16* wsb = (__hip_bfloat16*)d_ws;
  const size_t SZ = (size_t)8192 * 512;
  const size_t MS = (size_t)512 * 512;

  // Fixed low region (both paths):
  //   xb [0,SZ) | WT [SZ, SZ+24MS) | bfused (2048 f32) | bqkvb (9x512 bf16)
  //   proj area from SZ + 24MS + 16384 elems.
  __hip_bfloat16* xb    = wsb;
  __hip_bfloat16* WT    = wsb + SZ;
  float* bfused = (float*)(wsb + SZ + 24 * MS);             // 4096 bf16 elems
  __hip_bfloat16* bqkvb = wsb + SZ + 24 * MS + 4096;        // 4608 elems
  __hip_bfloat16* proj  = wsb + SZ + 24 * MS + 16384;

  const size_t need_big = 2 * (17 * SZ + 24 * MS + 16384);  // bytes
  const bool big = ws_size >= need_big;

  const dim3 thr(256);

  // ---- one-time prep ----
  prep_weights_kernel<<<dim3(256, 22), thr, 0, stream>>>(
      loc_wq, loc_wk, loc_wv, g_wq, g_wk, g_wv, out_w, loc_wo, g_wo,
      x, loc_bq, loc_bk, loc_bv, WT, xb, bqkvb);
  gemm_fusew_kernel<<<dim3(4, 4, 4), thr, 0, stream>>>(WT + 12 * MS, WT + 16 * MS,
                                                       WT + 20 * MS);
  bias_fuse_kernel<<<dim3(2, 4), thr, 0, stream>>>(loc_bo, g_bo, out_w, out_b, bfused);

  __hip_bfloat16 *abar0, *abar1, *abar2, *abar3;

  if (big) {
    // ---- mega path: all 12 projections in one dispatch ----
    abar0 = proj + 12 * SZ;
    abar1 = proj + 13 * SZ;
    abar2 = proj + 14 * SZ;
    abar3 = proj + 15 * SZ;
    gemm_qkv_all_kernel<<<dim3(4, 64, 12), thr, 0, stream>>>(
        xb, WT, loc_bq, loc_bk, loc_bv, g_bq, g_bk, g_bv, proj);
    // locals: Xq = proj[lv], Xk = proj[3+lv], Xv = proj[6+lv]
    local_attn_mfma_kernel<3><<<2048, thr, 0, stream>>>(
        proj + 0 * SZ, proj + 3 * SZ, proj + 6 * SZ,
        bqkvb + 0 * 512, bqkvb + 1 * 512, bqkvb + 2 * 512, abar0);
    local_attn_mfma_kernel<5><<<2048, thr, 0, stream>>>(
        proj + 1 * SZ, proj + 4 * SZ, proj + 7 * SZ,
        bqkvb + 3 * 512, bqkvb + 4 * 512, bqkvb + 5 * 512, abar1);
    local_attn_mfma_kernel<7><<<2048, thr, 0, stream>>>(
        proj + 2 * SZ, proj + 5 * SZ, proj + 8 * SZ,
        bqkvb + 6 * 512, bqkvb + 7 * 512, bqkvb + 8 * 512, abar2);
    global_attn_mfma_kernel<<<dim3(8, 64), thr, 0, stream>>>(
        proj + 9 * SZ, proj + 10 * SZ, proj + 11 * SZ, abar3);
  } else {
    // ---- fallback: R9 serialized path (3 shared buffers) ----
    __hip_bfloat16* Xq = proj;
    __hip_bfloat16* Xk = proj + SZ;
    __hip_bfloat16* Xv = proj + 2 * SZ;
    abar0 = proj + 3 * SZ;
    abar1 = proj + 4 * SZ;
    abar2 = proj + 5 * SZ;
    abar3 = proj + 6 * SZ;
    __hip_bfloat16* abars[3] = {abar0, abar1, abar2};
    const dim3 gqkv(4, 64, 3);
    for (int lv = 0; lv < 3; ++lv) {
      gemm_qkv_kernel<<<gqkv, thr, 0, stream>>>(
          xb, WT + lv * MS, 3 * MS,
          loc_bq + lv * 512, loc_bk + lv * 512, loc_bv + lv * 512, Xq);
      const __hip_bfloat16* bqb = bqkvb + (lv * 3 + 0) * 512;
      const __hip_bfloat16* bkb = bqkvb + (lv * 3 + 1) * 512;
      const __hip_bfloat16* bvb = bqkvb + (lv * 3 + 2) * 512;
      if (lv == 0)
        local_attn_mfma_kernel<3><<<2048, thr, 0, stream>>>(Xq, Xk, Xv, bqb, bkb, bvb, abars[lv]);
      else if (lv == 1)
        local_attn_mfma_kernel<5><<<2048, thr, 0, stream>>>(Xq, Xk, Xv, bqb, bkb, bvb, abars[lv]);
      else
        local_attn_mfma_kernel<7><<<2048, thr, 0, stream>>>(Xq, Xk, Xv, bqb, bkb, bvb, abars[lv]);
    }
    gemm_qkv_kernel<<<gqkv, thr, 0, stream>>>(xb, WT + 9 * MS, MS, g_bq, g_bk, g_bv, Xq);
    global_attn_mfma_kernel<<<dim3(8, 64), thr, 0, stream>>>(Xq, Xk, Xv, abar3);
  }

  // fused output projection: one K=2048 GEMM (BM=64), out written once
  gemm_out_fused_kernel<<<dim3(4, 128), thr, 0, stream>>>(abar0, abar1, abar2, abar3,
                                                          WT + 20 * MS, bfused, out);
}